// Round 2
// baseline (695.981 us; speedup 1.0000x reference)
//
#include <hip/hip_runtime.h>
#include <hip/hip_bf16.h>
#include <stdint.h>

typedef __hip_bfloat16 bf16;
typedef __attribute__((ext_vector_type(8))) short short8;   // 8 bf16 = 4 VGPRs (MFMA A/B frag)
typedef __attribute__((ext_vector_type(4))) float f32x4;    // MFMA C/D frag
typedef __attribute__((ext_vector_type(2))) unsigned uint2v;
typedef __attribute__((ext_vector_type(4))) unsigned uint4v;
typedef __attribute__((ext_vector_type(4))) unsigned short ushort4v;

#define B_   4
#define S_   4096
#define D_   1024
#define KSEL 2048
#define DFF  4096
#define NH   16
#define DH   64

// ---------------------------------------------------------------- helpers
static __device__ __forceinline__ void load_lds16(const void* g, void* l) {
  // async global->LDS, 16B per lane, dst = wave-uniform base + lane*16
  __builtin_amdgcn_global_load_lds((const __attribute__((address_space(1))) void*)g,
                                   (__attribute__((address_space(3))) void*)l,
                                   16, 0, 0);
}

static __device__ __forceinline__ short8 scale8(short8 v, float s) {
  // bf16 *= s; no address-of on vector elements
  short8 r;
#pragma unroll
  for (int i = 0; i < 8; ++i) {
    unsigned u = ((unsigned)(unsigned short)v[i]) << 16;
    float f = __uint_as_float(u) * s;
    bf16 o = __float2bfloat16(f);
    short t;
    __builtin_memcpy(&t, &o, 2);
    r[i] = t;
  }
  return r;
}

static __device__ __forceinline__ unsigned cvt_pk_bf16(float lo, float hi) {
  // dst.lo = bf16(lo), dst.hi = bf16(hi)  (no builtin on gfx950 -- T12 recipe)
  unsigned r;
  asm("v_cvt_pk_bf16_f32 %0, %1, %2" : "=v"(r) : "v"(lo), "v"(hi));
  return r;
}

static __device__ __forceinline__ void pl32_swap(unsigned &a, unsigned &b) {
  // a' = {a[0:31], b[0:31]}, b' = {a[32:63], b[32:63]}
#if __has_builtin(__builtin_amdgcn_permlane32_swap)
  uint2v r = __builtin_amdgcn_permlane32_swap(a, b, false, false);
  a = r[0]; b = r[1];
#else
  asm("v_permlane32_swap_b32 %0, %1" : "+v"(a), "+v"(b));
#endif
}

static __device__ __forceinline__ void pl16_swap(unsigned &a, unsigned &b) {
  // a' = {a.r0, b.r0, a.r2, b.r2}, b' = {a.r1, b.r1, a.r3, b.r3}  (16-lane rows)
#if __has_builtin(__builtin_amdgcn_permlane16_swap)
  uint2v r = __builtin_amdgcn_permlane16_swap(a, b, false, false);
  a = r[0]; b = r[1];
#else
  asm("v_permlane16_swap_b32 %0, %1" : "+v"(a), "+v"(b));
#endif
}

// ---------------------------------------------------------------- 1) copy x -> out, logits = x @ router_w
__global__ __launch_bounds__(256)
void copy_router(const float* __restrict__ x, const float* __restrict__ rwts,
                 float* __restrict__ out, float* __restrict__ logits)
{
  int s = blockIdx.x, b = blockIdx.y;
  int tid = threadIdx.x;
  const float4* row = (const float4*)(x + ((size_t)b * S_ + s) * D_);
  float4 v = row[tid];
  ((float4*)(out + ((size_t)b * S_ + s) * D_))[tid] = v;
  float4 rv = ((const float4*)rwts)[tid];
  float p = v.x * rv.x + v.y * rv.y + v.z * rv.z + v.w * rv.w;
  for (int off = 32; off; off >>= 1) p += __shfl_down(p, off, 64);
  __shared__ float wsum[4];
  if ((tid & 63) == 0) wsum[tid >> 6] = p;
  __syncthreads();
  if (tid == 0) logits[(size_t)b * S_ + s] = wsum[0] + wsum[1] + wsum[2] + wsum[3];
}

// ---------------------------------------------------------------- 2) per-batch top-K select + softmax weights
__global__ __launch_bounds__(1024)
void topk_kernel(const float* __restrict__ logits,
                 int* __restrict__ sel, float* __restrict__ rw)
{
  __shared__ float lg[4096];
  __shared__ unsigned long long keys[4096];
  __shared__ unsigned char flags[4096];
  __shared__ float wsum[16];
  __shared__ int wtot[16];
  __shared__ int woff[17];

  int b = blockIdx.x, tid = threadIdx.x;
  const float* L = logits + (size_t)b * S_;
  for (int i = tid; i < 4096; i += 1024) {
    float v = L[i];
    lg[i] = v;
    unsigned u = __float_as_uint(v);
    u = (u & 0x80000000u) ? ~u : (u | 0x80000000u);  // total order, ascending
    u = ~u;                                          // descending by value
    keys[i] = ((unsigned long long)u << 32) | (unsigned)i;  // tie -> smaller idx first
  }
  __syncthreads();
  // bitonic sort ascending (=> value desc, idx asc) : matches jax.top_k semantics
  for (int k = 2; k <= 4096; k <<= 1) {
    for (int j = k >> 1; j > 0; j >>= 1) {
      for (int t = tid; t < 4096; t += 1024) {
        int ixj = t ^ j;
        if (ixj > t) {
          bool up = ((t & k) == 0);
          unsigned long long a = keys[t], c = keys[ixj];
          if ((a > c) == up) { keys[t] = c; keys[ixj] = a; }
        }
      }
      __syncthreads();
    }
  }
  // mark selected
  for (int i = tid; i < 4096; i += 1024) flags[i] = 0;
  __syncthreads();
  for (int i = tid; i < KSEL; i += 1024) flags[(int)(keys[i] & 0xFFFFFFFFu)] = 1;
  __syncthreads();
  float m = lg[(int)(keys[0] & 0xFFFFFFFFu)];  // max selected logit
  // softmax denominator over selected
  float part = 0.f;
  for (int i = tid; i < KSEL; i += 1024) part += __expf(lg[(int)(keys[i] & 0xFFFFFFFFu)] - m);
  for (int off = 32; off; off >>= 1) part += __shfl_down(part, off, 64);
  if ((tid & 63) == 0) wsum[tid >> 6] = part;
  __syncthreads();
  if (tid == 0) { float t = 0; for (int w = 0; w < 16; ++w) t += wsum[w]; wsum[0] = t; }
  __syncthreads();
  float inv = 1.0f / wsum[0];
  // compact ascending via prefix scan (4 flags/thread)
  int base = tid * 4;
  int f0 = flags[base], f1 = flags[base + 1], f2 = flags[base + 2], f3 = flags[base + 3];
  int mysum = f0 + f1 + f2 + f3;
  int incl = mysum;
  int lane = tid & 63;
  for (int off = 1; off < 64; off <<= 1) {
    int t = __shfl_up(incl, off, 64);
    if (lane >= off) incl += t;
  }
  if (lane == 63) wtot[tid >> 6] = incl;
  __syncthreads();
  if (tid == 0) { int sacc = 0; for (int w = 0; w < 16; ++w) { woff[w] = sacc; sacc += wtot[w]; } woff[16] = sacc; }
  __syncthreads();
  int p = woff[tid >> 6] + incl - mysum;
  int fl[4] = { f0, f1, f2, f3 };
  for (int q = 0; q < 4; ++q) {
    if (fl[q]) {
      int idx = base + q;
      sel[b * KSEL + p] = idx;
      rw[b * KSEL + p] = __expf(lg[idx] - m) * inv;
      p++;
    }
  }
}

// ---------------------------------------------------------------- 3) LayerNorm (optional gather) -> bf16
__global__ __launch_bounds__(256)
void ln_kernel(const float* __restrict__ in, const float* __restrict__ x,
               const int* __restrict__ sel,
               const float* __restrict__ g, const float* __restrict__ beta,
               bf16* __restrict__ out, int gather)
{
  int r = blockIdx.x;
  int tid = threadIdx.x;
  const float* src;
  if (gather) {
    int b = r >> 11, t = r & 2047;
    src = x + ((size_t)b * S_ + sel[b * KSEL + t]) * D_;
  } else {
    src = in + (size_t)r * D_;
  }
  float4 v = ((const float4*)src)[tid];
  float s = v.x + v.y + v.z + v.w;
  float sq = v.x * v.x + v.y * v.y + v.z * v.z + v.w * v.w;
  for (int off = 32; off; off >>= 1) { s += __shfl_down(s, off, 64); sq += __shfl_down(sq, off, 64); }
  __shared__ float wsA[4], wsB[4];
  if ((tid & 63) == 0) { wsA[tid >> 6] = s; wsB[tid >> 6] = sq; }
  __syncthreads();
  float stot = wsA[0] + wsA[1] + wsA[2] + wsA[3];
  float sqt  = wsB[0] + wsB[1] + wsB[2] + wsB[3];
  float mean = stot * (1.f / 1024.f);
  float var  = sqt * (1.f / 1024.f) - mean * mean;
  float rs = rsqrtf(var + 1e-5f);
  float4 gv = ((const float4*)g)[tid];
  float4 bv = ((const float4*)beta)[tid];
  bf16* o = out + (size_t)r * D_ + tid * 4;
  o[0] = __float2bfloat16((v.x - mean) * rs * gv.x + bv.x);
  o[1] = __float2bfloat16((v.y - mean) * rs * gv.y + bv.y);
  o[2] = __float2bfloat16((v.z - mean) * rs * gv.z + bv.z);
  o[3] = __float2bfloat16((v.w - mean) * rs * gv.w + bv.w);
}

// ---------------------------------------------------------------- 4) weight cast+transpose fp32[K][N] -> bf16[N][K]
__global__ __launch_bounds__(256)
void wtrans(const float* __restrict__ in, bf16* __restrict__ out, int K, int N)
{
  __shared__ float tile[32][33];
  int n0 = blockIdx.x * 32, k0 = blockIdx.y * 32;
  int r = threadIdx.x >> 5, c = threadIdx.x & 31;
#pragma unroll
  for (int i = 0; i < 4; ++i)
    tile[r + 8 * i][c] = in[(size_t)(k0 + r + 8 * i) * N + n0 + c];
  __syncthreads();
#pragma unroll
  for (int i = 0; i < 4; ++i)
    out[(size_t)(n0 + r + 8 * i) * K + k0 + c] = __float2bfloat16(tile[c][r + 8 * i]);
}

// ---------------------------------------------------------------- 5) V transpose: qkv[t][2048+h*64+d] -> vt[bh][d][t]
__global__ __launch_bounds__(256)
void vt_transpose(const bf16* __restrict__ qkv, bf16* __restrict__ vt)
{
  __shared__ bf16 tile[32][33];
  int bh = blockIdx.z;
  int d0 = blockIdx.y * 32;
  int t0 = blockIdx.x * 32;
  int b = bh >> 4, h = bh & 15;
  int r = threadIdx.x >> 5, c = threadIdx.x & 31;
#pragma unroll
  for (int i = 0; i < 4; ++i) {
    int t = t0 + r + 8 * i;
    tile[r + 8 * i][c] = qkv[(size_t)(b * KSEL + t) * 3072 + 2048 + h * 64 + d0 + c];
  }
  __syncthreads();
#pragma unroll
  for (int i = 0; i < 4; ++i) {
    int d = d0 + r + 8 * i;
    vt[((size_t)bh * 64 + d) * KSEL + t0 + c] = tile[c][r + 8 * i];
  }
}

// ---------------------------------------------------------------- 6) GEMM C = A(bf16 MxK) * Bt(bf16 NxK)^T  + fused epilogues
// EPI 0: store bf16            (QKV)
// EPI 1: Cf = gather(x) + acc  (o-proj residual, fp32)
// EPI 2: store bf16 gelu(acc)  (FFN1)
// EPI 3: out[b,sel,n] += rw*(x1 + acc)  (FFN2 + final scatter)
//        split-K over blockIdx.z (4 slices of K/4): each slice atomicAdds
//        rw*acc_z; slice 0 folds in the rw*x1 term. out is pre-seeded with x
//        by copy_router, so cross-slice accumulation is order-free fp32 adds.
template<int EPI>
__global__ __launch_bounds__(256)
void gemm_bt(const bf16* __restrict__ A, const bf16* __restrict__ Bt,
             float* __restrict__ Cf, bf16* __restrict__ Cb,
             int M, int N, int K,
             const float* __restrict__ xin, const int* __restrict__ sel,
             const float* __restrict__ rw, const float* __restrict__ x1,
             float* __restrict__ outp)
{
  __shared__ bf16 As[128 * 64];
  __shared__ bf16 Bs[128 * 64];
  const int tid = threadIdx.x;
  const int wid = tid >> 6;
  const int lane = tid & 63;
  const int l15 = lane & 15;
  const int quad = lane >> 4;
  const int wm = wid >> 1, wn = wid & 1;
  const int bm = blockIdx.x * 128;
  const int bn = blockIdx.y * 128;

  // split-K (EPI 3 only): gridDim.z = 4, each z owns a contiguous K/4 slice
  const int kz   = (EPI == 3) ? blockIdx.z : 0;
  const int Kz   = (EPI == 3) ? (K >> 2) : K;
  const int kbeg = kz * Kz;
  const int kend = kbeg + Kz;

  const int srow = lane >> 3;              // 0..7 row-in-chunk
  const int sgrp = (lane & 7) ^ srow;      // XOR-swizzled source col-group

  f32x4 acc[4][4] = {};

  for (int k0 = kbeg; k0 < kend; k0 += 64) {
#pragma unroll
    for (int c2 = 0; c2 < 4; ++c2) {
      int c = wid * 4 + c2;
      const bf16* ga = A + (size_t)(bm + c * 8 + srow) * K + (k0 + sgrp * 8);
      load_lds16(ga, &As[c * 512]);
      const bf16* gb = Bt + (size_t)(bn + c * 8 + srow) * K + (k0 + sgrp * 8);
      load_lds16(gb, &Bs[c * 512]);
    }
    __syncthreads();
#pragma unroll
    for (int ks = 0; ks < 2; ++ks) {
      short8 af[4], bfv[4];
#pragma unroll
      for (int mt = 0; mt < 4; ++mt) {
        int row = wm * 64 + mt * 16 + l15;
        int cg = (ks * 4 + quad) ^ (row & 7);
        af[mt] = *(const short8*)&As[row * 64 + cg * 8];
      }
#pragma unroll
      for (int nt = 0; nt < 4; ++nt) {
        int row = wn * 64 + nt * 16 + l15;
        int cg = (ks * 4 + quad) ^ (row & 7);
        bfv[nt] = *(const short8*)&Bs[row * 64 + cg * 8];
      }
#pragma unroll
      for (int mt = 0; mt < 4; ++mt)
#pragma unroll
        for (int nt = 0; nt < 4; ++nt)
          acc[mt][nt] = __builtin_amdgcn_mfma_f32_16x16x32_bf16(af[mt], bfv[nt], acc[mt][nt], 0, 0, 0);
    }
    __syncthreads();
  }

#pragma unroll
  for (int mt = 0; mt < 4; ++mt) {
#pragma unroll
    for (int r = 0; r < 4; ++r) {
      int gm = bm + wm * 64 + mt * 16 + quad * 4 + r;
      int bb = gm >> 11, tt = gm & 2047;
      int sr = 0; float rwv = 0.f;
      if (EPI == 1 || EPI == 3) sr = sel[bb * KSEL + tt];
      if (EPI == 3) rwv = rw[bb * KSEL + tt];
#pragma unroll
      for (int nt = 0; nt < 4; ++nt) {
        int gn = bn + wn * 64 + nt * 16 + l15;
        float v = acc[mt][nt][r];
        if (EPI == 0) {
          Cb[(size_t)gm * N + gn] = __float2bfloat16(v);
        } else if (EPI == 1) {
          float xv = xin[((size_t)bb * S_ + sr) * D_ + gn];
          Cf[(size_t)gm * N + gn] = xv + v;
        } else if (EPI == 2) {
          float u = v;
          float cc = 0.7978845608028654f * (u + 0.044715f * u * u * u);
          float e = __expf(2.f * cc);
          float th = 1.f - 2.f / (e + 1.f);
          Cb[(size_t)gm * N + gn] = __float2bfloat16(0.5f * u * (1.f + th));
        } else {
          float v2 = rwv * v;
          if (kz == 0) v2 += rwv * x1[(size_t)gm * D_ + gn];
          atomicAdd(&outp[((size_t)bb * S_ + sr) * D_ + gn], v2);
        }
      }
    }
  }
}

// ---------------------------------------------------------------- 7) flash attention, swapped-operand + in-register P
// Block: 4 waves, 128 q-rows of one (b,h). Per K-tile: stage K(128x64) and
// V^T(64x128) into LDS (XOR-swizzled async global_load_lds); all LDS reads
// are conflict-free ds_read_b128.
// QK^T is computed operand-SWAPPED: S^T = mfma(K_frag, Q_frag), so each lane
// holds P values for a single q-column (q = lane&15). P never touches LDS:
// v_cvt_pk_bf16_f32 pairs + permlane32_swap + permlane16_swap rebuild the
// exact B-fragment of O^T = V^T * P^T in registers (T12). Lane (quad',l15)
// B-frag word t needs P^T[k = ks4*32 + quad'*8 + 2t+e][l15], which lives in
// source quad 2*(quad'&1)+(t>>1), cvt_pk word (t&1):
//   {w_t0, w_t2} = permlane16_swap(permlane32_swap(A_v, B_v))
// Softmax: no max tracking (|s|<~3 by construction), exp2 with log2e folded
// into the Q prescale, l-reduction over quads in the epilogue.
__global__ __launch_bounds__(256)
void flash_kernel(const bf16* __restrict__ qkv, const bf16* __restrict__ vt,
                  bf16* __restrict__ attn_o)
{
  __shared__ bf16 Ks[128 * 64];        // [token][dh]   16 KB
  __shared__ bf16 Vs[64 * 128];        // [dh][token]   16 KB
  int qt = blockIdx.x, h = blockIdx.y, b = blockIdx.z;
  int tid = threadIdx.x, wid = tid >> 6, lane = tid & 63;
  int l15 = lane & 15, quad = lane >> 4;
  int q0 = qt * 128 + wid * 32;

  const int srowK = lane >> 3, sgK = lane & 7;   // Ks staging: 8 rows / inst
  const int srowV = lane >> 4, sgV = lane & 15;  // Vs staging: 4 rows / inst

  // Q fragments, pre-scaled by (1/8)*log2(e) so scores feed exp2.
  // Per-lane layout is identical for A- and B-frags (row/col = l15,
  // k = quad*8+j), so the same registers serve as the B operand of S^T.
  short8 qf[2][2];
#pragma unroll
  for (int mt = 0; mt < 2; ++mt)
#pragma unroll
    for (int ks = 0; ks < 2; ++ks) {
      const bf16* p = qkv + (size_t)(b * KSEL + q0 + mt * 16 + l15) * 3072 + h * 64 + ks * 32 + quad * 8;
      qf[mt][ks] = scale8(*(const short8*)p, 0.125f * 1.44269504f);
    }

  f32x4 acc_ot[2][4] = {};   // O^T: lane holds O^T[dh=dt*16+quad*4+r][q=mt*16+l15]
  float lsum[2] = {};

  const bf16* Vg = vt + (size_t)(b * NH + h) * 64 * KSEL;

  for (int kt = 0; kt < KSEL / 128; ++kt) {
    int tok0 = b * KSEL + kt * 128;
    __syncthreads();   // previous tile's LDS reads complete
#pragma unroll
    for (int i = 0; i < 4; ++i) {
      int c = wid * 4 + i;
      const bf16* ga = qkv + (size_t)(tok0 + c * 8 + srowK) * 3072 + 1024 + h * 64 + ((sgK ^ srowK) * 8);
      load_lds16(ga, &Ks[c * 512]);
      int vr = c * 4 + srowV;
      const bf16* gv = Vg + (size_t)vr * KSEL + kt * 128 + ((sgV ^ (vr & 7)) * 8);
      load_lds16(gv, &Vs[c * 512]);
    }
    __syncthreads();   // staging drained (vmcnt(0) before s_barrier)

#pragma unroll
    for (int ks4 = 0; ks4 < 4; ++ks4) {
      // ---- QK^T (swapped): S^T tiles for the two 16-token groups of this 32-k block
      f32x4 s[2][2] = {};   // [mt][u]
#pragma unroll
      for (int u = 0; u < 2; ++u) {
        int row = (ks4 * 2 + u) * 16 + l15;
#pragma unroll
        for (int ks = 0; ks < 2; ++ks) {
          int g = (ks * 4 + quad) ^ (row & 7);
          short8 kf = *(const short8*)&Ks[row * 64 + g * 8];
#pragma unroll
          for (int mt = 0; mt < 2; ++mt)
            s[mt][u] = __builtin_amdgcn_mfma_f32_16x16x32_bf16(kf, qf[mt][ks], s[mt][u], 0, 0, 0);
        }
      }
      // ---- softmax + in-register transpose into P^T B-fragments
      short8 pfrag[2];
#pragma unroll
      for (int mt = 0; mt < 2; ++mt) {
        float pA[4], pB[4];
#pragma unroll
        for (int r = 0; r < 4; ++r) {
          pA[r] = __builtin_amdgcn_exp2f(s[mt][0][r]);
          pB[r] = __builtin_amdgcn_exp2f(s[mt][1][r]);
          lsum[mt] += pA[r] + pB[r];
        }
        unsigned A0 = cvt_pk_bf16(pA[0], pA[1]);
        unsigned A1 = cvt_pk_bf16(pA[2], pA[3]);
        unsigned B0 = cvt_pk_bf16(pB[0], pB[1]);
        unsigned B1 = cvt_pk_bf16(pB[2], pB[3]);
        pl32_swap(A0, B0); pl16_swap(A0, B0);   // A0 -> word t0, B0 -> word t2
        pl32_swap(A1, B1); pl16_swap(A1, B1);   // A1 -> word t1, B1 -> word t3
        uint4v w; w[0] = A0; w[1] = A1; w[2] = B0; w[3] = B1;
        pfrag[mt] = __builtin_bit_cast(short8, w);
      }
      // ---- PV (transposed): O^T += V^T[:, k-block] * P^T[k-block, :]
#pragma unroll
      for (int dt = 0; dt < 4; ++dt) {
        int row = dt * 16 + l15;
        int g = (ks4 * 4 + quad) ^ (row & 7);
        short8 vf = *(const short8*)&Vs[row * 128 + g * 8];
#pragma unroll
        for (int mt = 0; mt < 2; ++mt)
          acc_ot[mt][dt] = __builtin_amdgcn_mfma_f32_16x16x32_bf16(vf, pfrag[mt], acc_ot[mt][dt], 0, 0, 0);
      }
    }
  }
  // l lives per-lane for q = mt*16+l15, partial over this lane's quad; sum quads
#pragma unroll
  for (int mt = 0; mt < 2; ++mt) {
    float l = lsum[mt];
    l += __shfl_xor(l, 16, 64);
    l += __shfl_xor(l, 32, 64);
    float invl = 1.0f / l;
#pragma unroll
    for (int dt = 0; dt < 4; ++dt) {
      ushort4v o;
#pragma unroll
      for (int r = 0; r < 4; ++r) {
        bf16 t = __float2bfloat16(acc_ot[mt][dt][r] * invl);
        unsigned short us;
        __builtin_memcpy(&us, &t, 2);
        o[r] = us;
      }
      // 4 consecutive dh per lane -> one 8B store; quads tile 32B contiguous
      *(ushort4v*)(attn_o + (size_t)(b * KSEL + q0 + mt * 16 + l15) * D_ + h * 64 + dt * 16 + quad * 4) = o;
    }
  }
}

// ---------------------------------------------------------------- launch
extern "C" void kernel_launch(void* const* d_in, const int* in_sizes, int n_in,
                              void* d_out, int out_size, void* d_ws, size_t ws_size,
                              hipStream_t stream)
{
  const float* x      = (const float*)d_in[0];
  const float* router = (const float*)d_in[1];
  const float* ln1g   = (const float*)d_in[2];
  const float* ln1b   = (const float*)d_in[3];
  const float* ln2g   = (const float*)d_in[4];
  const float* ln2b   = (const float*)d_in[5];
  const float* wqkv   = (const float*)d_in[6];
  const float* wo     = (const float*)d_in[7];
  const float* w1     = (const float*)d_in[8];
  const float* w2     = (const float*)d_in[9];
  float* out = (float*)d_out;
  char* ws = (char*)d_ws;

  // workspace layout (all offsets 256B-aligned); total ~136.1 MB
  float* logits = (float*)(ws + 0);                 // 64 KB
  int*   sel    = (int*)  (ws + 65536);             // 32 KB
  float* rw     = (float*)(ws + 98304);             // 32 KB
  bf16* wqkvT   = (bf16*) (ws + 131072);            // 6 MB   [3072][1024]
  bf16* woT     = (bf16*) (ws + 6422528);           // 2 MB   [1024][1024]
  bf16* w1T     = (bf16*) (ws + 8519680);           // 8 MB   [4096][1024]
  bf16* w2T     = (bf16*) (ws + 16908288);          // 8 MB   [1024][4096]
  bf16* regA    = (bf16*) (ws + 25296896);          // 16 MB  h1 / attn_o / h2
  bf16* regB    = (bf16*) (ws + 42074112);          // 64 MB  qkv(48)+vt(16) then ffn_h
  bf16* vtb     = (bf16*) (ws + 42074112 + 50331648);
  float* x1     = (float*)(ws + 109182976);         // 32 MB

  copy_router<<<dim3(S_, B_), 256, 0, stream>>>(x, router, out, logits);
  topk_kernel<<<B_, 1024, 0, stream>>>(logits, sel, rw);

  wtrans<<<dim3(3072 / 32, 1024 / 32), 256, 0, stream>>>(wqkv, wqkvT, 1024, 3072);
  wtrans<<<dim3(1024 / 32, 1024 / 32), 256, 0, stream>>>(wo,   woT,   1024, 1024);
  wtrans<<<dim3(4096 / 32, 1024 / 32), 256, 0, stream>>>(w1,   w1T,   1024, 4096);
  wtrans<<<dim3(1024 / 32, 4096 / 32), 256, 0, stream>>>(w2,   w2T,   4096, 1024);

  ln_kernel<<<B_ * KSEL, 256, 0, stream>>>(nullptr, x, sel, ln1g, ln1b, regA, 1);

  // QKV: [8192x1024] * [3072x1024]^T -> bf16 [8192][3072]
  gemm_bt<0><<<dim3(64, 24), 256, 0, stream>>>(regA, wqkvT, nullptr, regB, 8192, 3072, 1024,
                                               nullptr, nullptr, nullptr, nullptr, nullptr);
  vt_transpose<<<dim3(KSEL / 32, 2, B_ * NH), 256, 0, stream>>>(regB, vtb);
  flash_kernel<<<dim3(KSEL / 128, NH, B_), 256, 0, stream>>>(regB, vtb, regA);

  // o-proj + gather residual: x1 = gather(x) + attn_o * wo
  gemm_bt<1><<<dim3(64, 8), 256, 0, stream>>>(regA, woT, x1, nullptr, 8192, 1024, 1024,
                                              x, sel, nullptr, nullptr, nullptr);
  ln_kernel<<<B_ * KSEL, 256, 0, stream>>>(x1, nullptr, nullptr, ln2g, ln2b, regA, 0);
  // FFN1 + gelu -> bf16 [8192][4096]
  gemm_bt<2><<<dim3(64, 32), 256, 0, stream>>>(regA, w1T, nullptr, regB, 8192, 4096, 1024,
                                               nullptr, nullptr, nullptr, nullptr, nullptr);
  // FFN2 + scatter (split-K=4): out[b,sel,:] += rw * (x1 + acc)
  gemm_bt<3><<<dim3(64, 8, 4), 256, 0, stream>>>(regB, w2T, nullptr, nullptr, 8192, 1024, 4096,
                                                 nullptr, sel, rw, x1, out);
}

// Round 3
// 645.694 us; speedup vs baseline: 1.0779x; 1.0779x over previous
//
#include <hip/hip_runtime.h>
#include <hip/hip_bf16.h>
#include <stdint.h>

typedef __hip_bfloat16 bf16;
typedef __attribute__((ext_vector_type(8))) short short8;   // 8 bf16 = 4 VGPRs (MFMA A/B frag)
typedef __attribute__((ext_vector_type(4))) float f32x4;    // MFMA C/D frag
typedef __attribute__((ext_vector_type(2))) unsigned uint2v;
typedef __attribute__((ext_vector_type(4))) unsigned uint4v;
typedef __attribute__((ext_vector_type(4))) unsigned short ushort4v;

#define B_   4
#define S_   4096
#define D_   1024
#define KSEL 2048
#define DFF  4096
#define NH   16
#define DH   64

// ---------------------------------------------------------------- helpers
static __device__ __forceinline__ void load_lds16(const void* g, void* l) {
  // async global->LDS, 16B per lane, dst = wave-uniform base + lane*16
  __builtin_amdgcn_global_load_lds((const __attribute__((address_space(1))) void*)g,
                                   (__attribute__((address_space(3))) void*)l,
                                   16, 0, 0);
}

static __device__ __forceinline__ short8 scale8(short8 v, float s) {
  // bf16 *= s; no address-of on vector elements
  short8 r;
#pragma unroll
  for (int i = 0; i < 8; ++i) {
    unsigned u = ((unsigned)(unsigned short)v[i]) << 16;
    float f = __uint_as_float(u) * s;
    bf16 o = __float2bfloat16(f);
    short t;
    __builtin_memcpy(&t, &o, 2);
    r[i] = t;
  }
  return r;
}

static __device__ __forceinline__ unsigned cvt_pk_bf16(float lo, float hi) {
  // dst.lo = bf16(lo), dst.hi = bf16(hi)  (no builtin on gfx950 -- T12 recipe)
  unsigned r;
  asm("v_cvt_pk_bf16_f32 %0, %1, %2" : "=v"(r) : "v"(lo), "v"(hi));
  return r;
}

static __device__ __forceinline__ void pl32_swap(unsigned &a, unsigned &b) {
  // a' = {a[0:31], b[0:31]}, b' = {a[32:63], b[32:63]}
#if __has_builtin(__builtin_amdgcn_permlane32_swap)
  uint2v r = __builtin_amdgcn_permlane32_swap(a, b, false, false);
  a = r[0]; b = r[1];
#else
  asm("v_permlane32_swap_b32 %0, %1" : "+v"(a), "+v"(b));
#endif
}

static __device__ __forceinline__ void pl16_swap(unsigned &a, unsigned &b) {
  // a' = {a.r0, b.r0, a.r2, b.r2}, b' = {a.r1, b.r1, a.r3, b.r3}  (16-lane rows)
#if __has_builtin(__builtin_amdgcn_permlane16_swap)
  uint2v r = __builtin_amdgcn_permlane16_swap(a, b, false, false);
  a = r[0]; b = r[1];
#else
  asm("v_permlane16_swap_b32 %0, %1" : "+v"(a), "+v"(b));
#endif
}

// ---------------------------------------------------------------- 1) copy x -> out, logits = x @ router_w
__global__ __launch_bounds__(256)
void copy_router(const float* __restrict__ x, const float* __restrict__ rwts,
                 float* __restrict__ out, float* __restrict__ logits)
{
  int s = blockIdx.x, b = blockIdx.y;
  int tid = threadIdx.x;
  const float4* row = (const float4*)(x + ((size_t)b * S_ + s) * D_);
  float4 v = row[tid];
  ((float4*)(out + ((size_t)b * S_ + s) * D_))[tid] = v;
  float4 rv = ((const float4*)rwts)[tid];
  float p = v.x * rv.x + v.y * rv.y + v.z * rv.z + v.w * rv.w;
  for (int off = 32; off; off >>= 1) p += __shfl_down(p, off, 64);
  __shared__ float wsum[4];
  if ((tid & 63) == 0) wsum[tid >> 6] = p;
  __syncthreads();
  if (tid == 0) logits[(size_t)b * S_ + s] = wsum[0] + wsum[1] + wsum[2] + wsum[3];
}

// ---------------------------------------------------------------- 2) per-batch top-K select + softmax weights
__global__ __launch_bounds__(1024)
void topk_kernel(const float* __restrict__ logits,
                 int* __restrict__ sel, float* __restrict__ rw)
{
  __shared__ float lg[4096];
  __shared__ unsigned long long keys[4096];
  __shared__ unsigned char flags[4096];
  __shared__ float wsum[16];
  __shared__ int wtot[16];
  __shared__ int woff[17];

  int b = blockIdx.x, tid = threadIdx.x;
  const float* L = logits + (size_t)b * S_;
  for (int i = tid; i < 4096; i += 1024) {
    float v = L[i];
    lg[i] = v;
    unsigned u = __float_as_uint(v);
    u = (u & 0x80000000u) ? ~u : (u | 0x80000000u);  // total order, ascending
    u = ~u;                                          // descending by value
    keys[i] = ((unsigned long long)u << 32) | (unsigned)i;  // tie -> smaller idx first
  }
  __syncthreads();
  // bitonic sort ascending (=> value desc, idx asc) : matches jax.top_k semantics
  for (int k = 2; k <= 4096; k <<= 1) {
    for (int j = k >> 1; j > 0; j >>= 1) {
      for (int t = tid; t < 4096; t += 1024) {
        int ixj = t ^ j;
        if (ixj > t) {
          bool up = ((t & k) == 0);
          unsigned long long a = keys[t], c = keys[ixj];
          if ((a > c) == up) { keys[t] = c; keys[ixj] = a; }
        }
      }
      __syncthreads();
    }
  }
  // mark selected
  for (int i = tid; i < 4096; i += 1024) flags[i] = 0;
  __syncthreads();
  for (int i = tid; i < KSEL; i += 1024) flags[(int)(keys[i] & 0xFFFFFFFFu)] = 1;
  __syncthreads();
  float m = lg[(int)(keys[0] & 0xFFFFFFFFu)];  // max selected logit
  // softmax denominator over selected
  float part = 0.f;
  for (int i = tid; i < KSEL; i += 1024) part += __expf(lg[(int)(keys[i] & 0xFFFFFFFFu)] - m);
  for (int off = 32; off; off >>= 1) part += __shfl_down(part, off, 64);
  if ((tid & 63) == 0) wsum[tid >> 6] = part;
  __syncthreads();
  if (tid == 0) { float t = 0; for (int w = 0; w < 16; ++w) t += wsum[w]; wsum[0] = t; }
  __syncthreads();
  float inv = 1.0f / wsum[0];
  // compact ascending via prefix scan (4 flags/thread)
  int base = tid * 4;
  int f0 = flags[base], f1 = flags[base + 1], f2 = flags[base + 2], f3 = flags[base + 3];
  int mysum = f0 + f1 + f2 + f3;
  int incl = mysum;
  int lane = tid & 63;
  for (int off = 1; off < 64; off <<= 1) {
    int t = __shfl_up(incl, off, 64);
    if (lane >= off) incl += t;
  }
  if (lane == 63) wtot[tid >> 6] = incl;
  __syncthreads();
  if (tid == 0) { int sacc = 0; for (int w = 0; w < 16; ++w) { woff[w] = sacc; sacc += wtot[w]; } woff[16] = sacc; }
  __syncthreads();
  int p = woff[tid >> 6] + incl - mysum;
  int fl[4] = { f0, f1, f2, f3 };
  for (int q = 0; q < 4; ++q) {
    if (fl[q]) {
      int idx = base + q;
      sel[b * KSEL + p] = idx;
      rw[b * KSEL + p] = __expf(lg[idx] - m) * inv;
      p++;
    }
  }
}

// ---------------------------------------------------------------- 3) LayerNorm (optional gather) -> bf16
__global__ __launch_bounds__(256)
void ln_kernel(const float* __restrict__ in, const float* __restrict__ x,
               const int* __restrict__ sel,
               const float* __restrict__ g, const float* __restrict__ beta,
               bf16* __restrict__ out, int gather)
{
  int r = blockIdx.x;
  int tid = threadIdx.x;
  const float* src;
  if (gather) {
    int b = r >> 11, t = r & 2047;
    src = x + ((size_t)b * S_ + sel[b * KSEL + t]) * D_;
  } else {
    src = in + (size_t)r * D_;
  }
  float4 v = ((const float4*)src)[tid];
  float s = v.x + v.y + v.z + v.w;
  float sq = v.x * v.x + v.y * v.y + v.z * v.z + v.w * v.w;
  for (int off = 32; off; off >>= 1) { s += __shfl_down(s, off, 64); sq += __shfl_down(sq, off, 64); }
  __shared__ float wsA[4], wsB[4];
  if ((tid & 63) == 0) { wsA[tid >> 6] = s; wsB[tid >> 6] = sq; }
  __syncthreads();
  float stot = wsA[0] + wsA[1] + wsA[2] + wsA[3];
  float sqt  = wsB[0] + wsB[1] + wsB[2] + wsB[3];
  float mean = stot * (1.f / 1024.f);
  float var  = sqt * (1.f / 1024.f) - mean * mean;
  float rs = rsqrtf(var + 1e-5f);
  float4 gv = ((const float4*)g)[tid];
  float4 bv = ((const float4*)beta)[tid];
  bf16* o = out + (size_t)r * D_ + tid * 4;
  o[0] = __float2bfloat16((v.x - mean) * rs * gv.x + bv.x);
  o[1] = __float2bfloat16((v.y - mean) * rs * gv.y + bv.y);
  o[2] = __float2bfloat16((v.z - mean) * rs * gv.z + bv.z);
  o[3] = __float2bfloat16((v.w - mean) * rs * gv.w + bv.w);
}

// ---------------------------------------------------------------- 4) weight cast+transpose fp32[K][N] -> bf16[N][K]
__global__ __launch_bounds__(256)
void wtrans(const float* __restrict__ in, bf16* __restrict__ out, int K, int N)
{
  __shared__ float tile[32][33];
  int n0 = blockIdx.x * 32, k0 = blockIdx.y * 32;
  int r = threadIdx.x >> 5, c = threadIdx.x & 31;
#pragma unroll
  for (int i = 0; i < 4; ++i)
    tile[r + 8 * i][c] = in[(size_t)(k0 + r + 8 * i) * N + n0 + c];
  __syncthreads();
#pragma unroll
  for (int i = 0; i < 4; ++i)
    out[(size_t)(n0 + r + 8 * i) * K + k0 + c] = __float2bfloat16(tile[c][r + 8 * i]);
}

// ---------------------------------------------------------------- 5) V transpose: qkv[t][2048+h*64+d] -> vt[bh][d][t]
__global__ __launch_bounds__(256)
void vt_transpose(const bf16* __restrict__ qkv, bf16* __restrict__ vt)
{
  __shared__ bf16 tile[32][33];
  int bh = blockIdx.z;
  int d0 = blockIdx.y * 32;
  int t0 = blockIdx.x * 32;
  int b = bh >> 4, h = bh & 15;
  int r = threadIdx.x >> 5, c = threadIdx.x & 31;
#pragma unroll
  for (int i = 0; i < 4; ++i) {
    int t = t0 + r + 8 * i;
    tile[r + 8 * i][c] = qkv[(size_t)(b * KSEL + t) * 3072 + 2048 + h * 64 + d0 + c];
  }
  __syncthreads();
#pragma unroll
  for (int i = 0; i < 4; ++i) {
    int d = d0 + r + 8 * i;
    vt[((size_t)bh * 64 + d) * KSEL + t0 + c] = tile[c][r + 8 * i];
  }
}

// ---------------------------------------------------------------- 6) GEMM C = A(bf16 MxK) * Bt(bf16 NxK)^T  + fused epilogues
// TN = N-tile (128 or 64). TN=64 doubles the grid for the N=1024 GEMMs
// (o-proj, FFN2): 512 -> 1024 blocks = 4 blocks/CU, LDS 24 KB.
// EPI 0: store bf16            (QKV)
// EPI 1: Cf = gather(x) + acc  (o-proj residual, fp32)
// EPI 2: store bf16 gelu(acc)  (FFN1)
// EPI 3: out[b,sel,n] += rw*(x1 + acc)  (FFN2 + final scatter; each (gm,gn)
//        owned by exactly one thread -- sel entries distinct -- plain RMW)
template<int EPI, int TN>
__global__ __launch_bounds__(256)
void gemm_bt(const bf16* __restrict__ A, const bf16* __restrict__ Bt,
             float* __restrict__ Cf, bf16* __restrict__ Cb,
             int M, int N, int K,
             const float* __restrict__ xin, const int* __restrict__ sel,
             const float* __restrict__ rw, const float* __restrict__ x1,
             float* __restrict__ outp)
{
  constexpr int NT = TN / 32;            // per-wave N fragments (2 waves split TN)
  constexpr int WN = TN / 2;             // per-wave N width
  __shared__ bf16 As[128 * 64];
  __shared__ bf16 Bs[TN * 64];
  const int tid = threadIdx.x;
  const int wid = tid >> 6;
  const int lane = tid & 63;
  const int l15 = lane & 15;
  const int quad = lane >> 4;
  const int wm = wid >> 1, wn = wid & 1;
  const int bm = blockIdx.x * 128;
  const int bn = blockIdx.y * TN;

  const int srow = lane >> 3;              // 0..7 row-in-chunk
  const int sgrp = (lane & 7) ^ srow;      // XOR-swizzled source col-group

  f32x4 acc[4][NT] = {};

  for (int k0 = 0; k0 < K; k0 += 64) {
#pragma unroll
    for (int c2 = 0; c2 < 4; ++c2) {
      int c = wid * 4 + c2;
      const bf16* ga = A + (size_t)(bm + c * 8 + srow) * K + (k0 + sgrp * 8);
      load_lds16(ga, &As[c * 512]);
    }
#pragma unroll
    for (int c2 = 0; c2 < TN / 32; ++c2) {
      int c = wid * (TN / 32) + c2;
      const bf16* gb = Bt + (size_t)(bn + c * 8 + srow) * K + (k0 + sgrp * 8);
      load_lds16(gb, &Bs[c * 512]);
    }
    __syncthreads();
#pragma unroll
    for (int ks = 0; ks < 2; ++ks) {
      short8 af[4], bfv[NT];
#pragma unroll
      for (int mt = 0; mt < 4; ++mt) {
        int row = wm * 64 + mt * 16 + l15;
        int cg = (ks * 4 + quad) ^ (row & 7);
        af[mt] = *(const short8*)&As[row * 64 + cg * 8];
      }
#pragma unroll
      for (int nt = 0; nt < NT; ++nt) {
        int row = wn * WN + nt * 16 + l15;
        int cg = (ks * 4 + quad) ^ (row & 7);
        bfv[nt] = *(const short8*)&Bs[row * 64 + cg * 8];
      }
#pragma unroll
      for (int mt = 0; mt < 4; ++mt)
#pragma unroll
        for (int nt = 0; nt < NT; ++nt)
          acc[mt][nt] = __builtin_amdgcn_mfma_f32_16x16x32_bf16(af[mt], bfv[nt], acc[mt][nt], 0, 0, 0);
    }
    __syncthreads();
  }

#pragma unroll
  for (int mt = 0; mt < 4; ++mt) {
#pragma unroll
    for (int r = 0; r < 4; ++r) {
      int gm = bm + wm * 64 + mt * 16 + quad * 4 + r;
      int bb = gm >> 11, tt = gm & 2047;
      int sr = 0; float rwv = 0.f;
      if (EPI == 1 || EPI == 3) sr = sel[bb * KSEL + tt];
      if (EPI == 3) rwv = rw[bb * KSEL + tt];
#pragma unroll
      for (int nt = 0; nt < NT; ++nt) {
        int gn = bn + wn * WN + nt * 16 + l15;
        float v = acc[mt][nt][r];
        if (EPI == 0) {
          Cb[(size_t)gm * N + gn] = __float2bfloat16(v);
        } else if (EPI == 1) {
          float xv = xin[((size_t)bb * S_ + sr) * D_ + gn];
          Cf[(size_t)gm * N + gn] = xv + v;
        } else if (EPI == 2) {
          float u = v;
          float cc = 0.7978845608028654f * (u + 0.044715f * u * u * u);
          float e = __expf(2.f * cc);
          float th = 1.f - 2.f / (e + 1.f);
          Cb[(size_t)gm * N + gn] = __float2bfloat16(0.5f * u * (1.f + th));
        } else {
          float v2 = rwv * (x1[(size_t)gm * D_ + gn] + v);
          outp[((size_t)bb * S_ + sr) * D_ + gn] += v2;
        }
      }
    }
  }
}

// ---------------------------------------------------------------- 7) flash attention, swapped-operand + in-register P
// Block: 4 waves, 128 q-rows of one (b,h). Per K-tile: stage K(128x64) and
// V^T(64x128) into LDS (XOR-swizzled async global_load_lds); all LDS reads
// are conflict-free ds_read_b128.
// QK^T is computed operand-SWAPPED: S^T = mfma(K_frag, Q_frag), so each lane
// holds P values for a single q-column (q = lane&15). P never touches LDS:
// v_cvt_pk_bf16_f32 pairs + permlane32_swap + permlane16_swap rebuild the
// exact B-fragment of O^T = V^T * P^T in registers (T12). Lane (quad',l15)
// B-frag word t needs P^T[k = ks4*32 + quad'*8 + 2t+e][l15], which lives in
// source quad 2*(quad'&1)+(t>>1), cvt_pk word (t&1):
//   {w_t0, w_t2} = permlane16_swap(permlane32_swap(A_v, B_v))
// Softmax: no max tracking (|s|<~3 by construction), exp2 with log2e folded
// into the Q prescale, l-reduction over quads in the epilogue.
__global__ __launch_bounds__(256)
void flash_kernel(const bf16* __restrict__ qkv, const bf16* __restrict__ vt,
                  bf16* __restrict__ attn_o)
{
  __shared__ bf16 Ks[128 * 64];        // [token][dh]   16 KB
  __shared__ bf16 Vs[64 * 128];        // [dh][token]   16 KB
  int qt = blockIdx.x, h = blockIdx.y, b = blockIdx.z;
  int tid = threadIdx.x, wid = tid >> 6, lane = tid & 63;
  int l15 = lane & 15, quad = lane >> 4;
  int q0 = qt * 128 + wid * 32;

  const int srowK = lane >> 3, sgK = lane & 7;   // Ks staging: 8 rows / inst
  const int srowV = lane >> 4, sgV = lane & 15;  // Vs staging: 4 rows / inst

  // Q fragments, pre-scaled by (1/8)*log2(e) so scores feed exp2.
  // Per-lane layout is identical for A- and B-frags (row/col = l15,
  // k = quad*8+j), so the same registers serve as the B operand of S^T.
  short8 qf[2][2];
#pragma unroll
  for (int mt = 0; mt < 2; ++mt)
#pragma unroll
    for (int ks = 0; ks < 2; ++ks) {
      const bf16* p = qkv + (size_t)(b * KSEL + q0 + mt * 16 + l15) * 3072 + h * 64 + ks * 32 + quad * 8;
      qf[mt][ks] = scale8(*(const short8*)p, 0.125f * 1.44269504f);
    }

  f32x4 acc_ot[2][4] = {};   // O^T: lane holds O^T[dh=dt*16+quad*4+r][q=mt*16+l15]
  float lsum[2] = {};

  const bf16* Vg = vt + (size_t)(b * NH + h) * 64 * KSEL;

  for (int kt = 0; kt < KSEL / 128; ++kt) {
    int tok0 = b * KSEL + kt * 128;
    __syncthreads();   // previous tile's LDS reads complete
#pragma unroll
    for (int i = 0; i < 4; ++i) {
      int c = wid * 4 + i;
      const bf16* ga = qkv + (size_t)(tok0 + c * 8 + srowK) * 3072 + 1024 + h * 64 + ((sgK ^ srowK) * 8);
      load_lds16(ga, &Ks[c * 512]);
      int vr = c * 4 + srowV;
      const bf16* gv = Vg + (size_t)vr * KSEL + kt * 128 + ((sgV ^ (vr & 7)) * 8);
      load_lds16(gv, &Vs[c * 512]);
    }
    __syncthreads();   // staging drained (vmcnt(0) before s_barrier)

#pragma unroll
    for (int ks4 = 0; ks4 < 4; ++ks4) {
      // ---- QK^T (swapped): S^T tiles for the two 16-token groups of this 32-k block
      f32x4 s[2][2] = {};   // [mt][u]
#pragma unroll
      for (int u = 0; u < 2; ++u) {
        int row = (ks4 * 2 + u) * 16 + l15;
#pragma unroll
        for (int ks = 0; ks < 2; ++ks) {
          int g = (ks * 4 + quad) ^ (row & 7);
          short8 kf = *(const short8*)&Ks[row * 64 + g * 8];
#pragma unroll
          for (int mt = 0; mt < 2; ++mt)
            s[mt][u] = __builtin_amdgcn_mfma_f32_16x16x32_bf16(kf, qf[mt][ks], s[mt][u], 0, 0, 0);
        }
      }
      // ---- softmax + in-register transpose into P^T B-fragments
      short8 pfrag[2];
#pragma unroll
      for (int mt = 0; mt < 2; ++mt) {
        float pA[4], pB[4];
#pragma unroll
        for (int r = 0; r < 4; ++r) {
          pA[r] = __builtin_amdgcn_exp2f(s[mt][0][r]);
          pB[r] = __builtin_amdgcn_exp2f(s[mt][1][r]);
          lsum[mt] += pA[r] + pB[r];
        }
        unsigned A0 = cvt_pk_bf16(pA[0], pA[1]);
        unsigned A1 = cvt_pk_bf16(pA[2], pA[3]);
        unsigned B0 = cvt_pk_bf16(pB[0], pB[1]);
        unsigned B1 = cvt_pk_bf16(pB[2], pB[3]);
        pl32_swap(A0, B0); pl16_swap(A0, B0);   // A0 -> word t0, B0 -> word t2
        pl32_swap(A1, B1); pl16_swap(A1, B1);   // A1 -> word t1, B1 -> word t3
        uint4v w; w[0] = A0; w[1] = A1; w[2] = B0; w[3] = B1;
        pfrag[mt] = __builtin_bit_cast(short8, w);
      }
      // ---- PV (transposed): O^T += V^T[:, k-block] * P^T[k-block, :]
#pragma unroll
      for (int dt = 0; dt < 4; ++dt) {
        int row = dt * 16 + l15;
        int g = (ks4 * 4 + quad) ^ (row & 7);
        short8 vf = *(const short8*)&Vs[row * 128 + g * 8];
#pragma unroll
        for (int mt = 0; mt < 2; ++mt)
          acc_ot[mt][dt] = __builtin_amdgcn_mfma_f32_16x16x32_bf16(vf, pfrag[mt], acc_ot[mt][dt], 0, 0, 0);
      }
    }
  }
  // l lives per-lane for q = mt*16+l15, partial over this lane's quad; sum quads
#pragma unroll
  for (int mt = 0; mt < 2; ++mt) {
    float l = lsum[mt];
    l += __shfl_xor(l, 16, 64);
    l += __shfl_xor(l, 32, 64);
    float invl = 1.0f / l;
#pragma unroll
    for (int dt = 0; dt < 4; ++dt) {
      ushort4v o;
#pragma unroll
      for (int r = 0; r < 4; ++r) {
        bf16 t = __float2bfloat16(acc_ot[mt][dt][r] * invl);
        unsigned short us;
        __builtin_memcpy(&us, &t, 2);
        o[r] = us;
      }
      // 4 consecutive dh per lane -> one 8B store; quads tile 32B contiguous
      *(ushort4v*)(attn_o + (size_t)(b * KSEL + q0 + mt * 16 + l15) * D_ + h * 64 + dt * 16 + quad * 4) = o;
    }
  }
}

// ---------------------------------------------------------------- launch
extern "C" void kernel_launch(void* const* d_in, const int* in_sizes, int n_in,
                              void* d_out, int out_size, void* d_ws, size_t ws_size,
                              hipStream_t stream)
{
  const float* x      = (const float*)d_in[0];
  const float* router = (const float*)d_in[1];
  const float* ln1g   = (const float*)d_in[2];
  const float* ln1b   = (const float*)d_in[3];
  const float* ln2g   = (const float*)d_in[4];
  const float* ln2b   = (const float*)d_in[5];
  const float* wqkv   = (const float*)d_in[6];
  const float* wo     = (const float*)d_in[7];
  const float* w1     = (const float*)d_in[8];
  const float* w2     = (const float*)d_in[9];
  float* out = (float*)d_out;
  char* ws = (char*)d_ws;

  // workspace layout (all offsets 256B-aligned); total ~136.1 MB
  float* logits = (float*)(ws + 0);                 // 64 KB
  int*   sel    = (int*)  (ws + 65536);             // 32 KB
  float* rw     = (float*)(ws + 98304);             // 32 KB
  bf16* wqkvT   = (bf16*) (ws + 131072);            // 6 MB   [3072][1024]
  bf16* woT     = (bf16*) (ws + 6422528);           // 2 MB   [1024][1024]
  bf16* w1T     = (bf16*) (ws + 8519680);           // 8 MB   [4096][1024]
  bf16* w2T     = (bf16*) (ws + 16908288);          // 8 MB   [1024][4096]
  bf16* regA    = (bf16*) (ws + 25296896);          // 16 MB  h1 / attn_o / h2
  bf16* regB    = (bf16*) (ws + 42074112);          // 64 MB  qkv(48)+vt(16) then ffn_h
  bf16* vtb     = (bf16*) (ws + 42074112 + 50331648);
  float* x1     = (float*)(ws + 109182976);         // 32 MB

  copy_router<<<dim3(S_, B_), 256, 0, stream>>>(x, router, out, logits);
  topk_kernel<<<B_, 1024, 0, stream>>>(logits, sel, rw);

  wtrans<<<dim3(3072 / 32, 1024 / 32), 256, 0, stream>>>(wqkv, wqkvT, 1024, 3072);
  wtrans<<<dim3(1024 / 32, 1024 / 32), 256, 0, stream>>>(wo,   woT,   1024, 1024);
  wtrans<<<dim3(4096 / 32, 1024 / 32), 256, 0, stream>>>(w1,   w1T,   1024, 4096);
  wtrans<<<dim3(1024 / 32, 4096 / 32), 256, 0, stream>>>(w2,   w2T,   4096, 1024);

  ln_kernel<<<B_ * KSEL, 256, 0, stream>>>(nullptr, x, sel, ln1g, ln1b, regA, 1);

  // QKV: [8192x1024] * [3072x1024]^T -> bf16 [8192][3072]
  gemm_bt<0, 128><<<dim3(64, 24), 256, 0, stream>>>(regA, wqkvT, nullptr, regB, 8192, 3072, 1024,
                                                    nullptr, nullptr, nullptr, nullptr, nullptr);
  vt_transpose<<<dim3(KSEL / 32, 2, B_ * NH), 256, 0, stream>>>(regB, vtb);
  flash_kernel<<<dim3(KSEL / 128, NH, B_), 256, 0, stream>>>(regB, vtb, regA);

  // o-proj + gather residual: x1 = gather(x) + attn_o * wo  (TN=64: 1024 blocks)
  gemm_bt<1, 64><<<dim3(64, 16), 256, 0, stream>>>(regA, woT, x1, nullptr, 8192, 1024, 1024,
                                                   x, sel, nullptr, nullptr, nullptr);
  ln_kernel<<<B_ * KSEL, 256, 0, stream>>>(x1, nullptr, nullptr, ln2g, ln2b, regA, 0);
  // FFN1 + gelu -> bf16 [8192][4096]
  gemm_bt<2, 128><<<dim3(64, 32), 256, 0, stream>>>(regA, w1T, nullptr, regB, 8192, 4096, 1024,
                                                    nullptr, nullptr, nullptr, nullptr, nullptr);
  // FFN2 + scatter: out[b,sel,:] += rw * (x1 + acc)  (TN=64: 1024 blocks)
  gemm_bt<3, 64><<<dim3(64, 16), 256, 0, stream>>>(regB, w2T, nullptr, nullptr, 8192, 1024, 4096,
                                                   nullptr, sel, rw, x1, out);
}

// Round 4
// 640.531 us; speedup vs baseline: 1.0866x; 1.0081x over previous
//
#include <hip/hip_runtime.h>
#include <hip/hip_bf16.h>
#include <stdint.h>

typedef __hip_bfloat16 bf16;
typedef __attribute__((ext_vector_type(8))) short short8;   // 8 bf16 = 4 VGPRs (MFMA A/B frag)
typedef __attribute__((ext_vector_type(4))) float f32x4;    // MFMA C/D frag
typedef __attribute__((ext_vector_type(2))) unsigned uint2v;
typedef __attribute__((ext_vector_type(4))) unsigned uint4v;
typedef __attribute__((ext_vector_type(4))) unsigned short ushort4v;

#define B_   4
#define S_   4096
#define D_   1024
#define KSEL 2048
#define DFF  4096
#define NH   16
#define DH   64

// ---------------------------------------------------------------- helpers
static __device__ __forceinline__ void load_lds16(const void* g, void* l) {
  // async global->LDS, 16B per lane, dst = wave-uniform base + lane*16
  __builtin_amdgcn_global_load_lds((const __attribute__((address_space(1))) void*)g,
                                   (__attribute__((address_space(3))) void*)l,
                                   16, 0, 0);
}

static __device__ __forceinline__ short8 scale8(short8 v, float s) {
  short8 r;
#pragma unroll
  for (int i = 0; i < 8; ++i) {
    unsigned u = ((unsigned)(unsigned short)v[i]) << 16;
    float f = __uint_as_float(u) * s;
    bf16 o = __float2bfloat16(f);
    short t;
    __builtin_memcpy(&t, &o, 2);
    r[i] = t;
  }
  return r;
}

static __device__ __forceinline__ unsigned cvt_pk_bf16(float lo, float hi) {
  unsigned r;
  asm("v_cvt_pk_bf16_f32 %0, %1, %2" : "=v"(r) : "v"(lo), "v"(hi));
  return r;
}

static __device__ __forceinline__ void pl32_swap(unsigned &a, unsigned &b) {
#if __has_builtin(__builtin_amdgcn_permlane32_swap)
  uint2v r = __builtin_amdgcn_permlane32_swap(a, b, false, false);
  a = r[0]; b = r[1];
#else
  asm("v_permlane32_swap_b32 %0, %1" : "+v"(a), "+v"(b));
#endif
}

static __device__ __forceinline__ void pl16_swap(unsigned &a, unsigned &b) {
#if __has_builtin(__builtin_amdgcn_permlane16_swap)
  uint2v r = __builtin_amdgcn_permlane16_swap(a, b, false, false);
  a = r[0]; b = r[1];
#else
  asm("v_permlane16_swap_b32 %0, %1" : "+v"(a), "+v"(b));
#endif
}

static __device__ __forceinline__ void wait_vm6() {
  asm volatile("s_waitcnt vmcnt(6)" ::: "memory");
  __builtin_amdgcn_sched_barrier(0);
}
static __device__ __forceinline__ void wait_vm0() {
  asm volatile("s_waitcnt vmcnt(0)" ::: "memory");
  __builtin_amdgcn_sched_barrier(0);
}

// ---------------------------------------------------------------- 1) copy x -> out, logits = x @ router_w
__global__ __launch_bounds__(256)
void copy_router(const float* __restrict__ x, const float* __restrict__ rwts,
                 float* __restrict__ out, float* __restrict__ logits)
{
  int s = blockIdx.x, b = blockIdx.y;
  int tid = threadIdx.x;
  const float4* row = (const float4*)(x + ((size_t)b * S_ + s) * D_);
  float4 v = row[tid];
  ((float4*)(out + ((size_t)b * S_ + s) * D_))[tid] = v;
  float4 rv = ((const float4*)rwts)[tid];
  float p = v.x * rv.x + v.y * rv.y + v.z * rv.z + v.w * rv.w;
  for (int off = 32; off; off >>= 1) p += __shfl_down(p, off, 64);
  __shared__ float wsum[4];
  if ((tid & 63) == 0) wsum[tid >> 6] = p;
  __syncthreads();
  if (tid == 0) logits[(size_t)b * S_ + s] = wsum[0] + wsum[1] + wsum[2] + wsum[3];
}

// ---------------------------------------------------------------- 2) per-batch top-K select + softmax weights
__global__ __launch_bounds__(1024)
void topk_kernel(const float* __restrict__ logits,
                 int* __restrict__ sel, float* __restrict__ rw)
{
  __shared__ float lg[4096];
  __shared__ unsigned long long keys[4096];
  __shared__ unsigned char flags[4096];
  __shared__ float wsum[16];
  __shared__ int wtot[16];
  __shared__ int woff[17];

  int b = blockIdx.x, tid = threadIdx.x;
  const float* L = logits + (size_t)b * S_;
  for (int i = tid; i < 4096; i += 1024) {
    float v = L[i];
    lg[i] = v;
    unsigned u = __float_as_uint(v);
    u = (u & 0x80000000u) ? ~u : (u | 0x80000000u);
    u = ~u;
    keys[i] = ((unsigned long long)u << 32) | (unsigned)i;
  }
  __syncthreads();
  for (int k = 2; k <= 4096; k <<= 1) {
    for (int j = k >> 1; j > 0; j >>= 1) {
      for (int t = tid; t < 4096; t += 1024) {
        int ixj = t ^ j;
        if (ixj > t) {
          bool up = ((t & k) == 0);
          unsigned long long a = keys[t], c = keys[ixj];
          if ((a > c) == up) { keys[t] = c; keys[ixj] = a; }
        }
      }
      __syncthreads();
    }
  }
  for (int i = tid; i < 4096; i += 1024) flags[i] = 0;
  __syncthreads();
  for (int i = tid; i < KSEL; i += 1024) flags[(int)(keys[i] & 0xFFFFFFFFu)] = 1;
  __syncthreads();
  float m = lg[(int)(keys[0] & 0xFFFFFFFFu)];
  float part = 0.f;
  for (int i = tid; i < KSEL; i += 1024) part += __expf(lg[(int)(keys[i] & 0xFFFFFFFFu)] - m);
  for (int off = 32; off; off >>= 1) part += __shfl_down(part, off, 64);
  if ((tid & 63) == 0) wsum[tid >> 6] = part;
  __syncthreads();
  if (tid == 0) { float t = 0; for (int w = 0; w < 16; ++w) t += wsum[w]; wsum[0] = t; }
  __syncthreads();
  float inv = 1.0f / wsum[0];
  int base = tid * 4;
  int f0 = flags[base], f1 = flags[base + 1], f2 = flags[base + 2], f3 = flags[base + 3];
  int mysum = f0 + f1 + f2 + f3;
  int incl = mysum;
  int lane = tid & 63;
  for (int off = 1; off < 64; off <<= 1) {
    int t = __shfl_up(incl, off, 64);
    if (lane >= off) incl += t;
  }
  if (lane == 63) wtot[tid >> 6] = incl;
  __syncthreads();
  if (tid == 0) { int sacc = 0; for (int w = 0; w < 16; ++w) { woff[w] = sacc; sacc += wtot[w]; } woff[16] = sacc; }
  __syncthreads();
  int p = woff[tid >> 6] + incl - mysum;
  int fl[4] = { f0, f1, f2, f3 };
  for (int q = 0; q < 4; ++q) {
    if (fl[q]) {
      int idx = base + q;
      sel[b * KSEL + p] = idx;
      rw[b * KSEL + p] = __expf(lg[idx] - m) * inv;
      p++;
    }
  }
}

// ---------------------------------------------------------------- 3) LayerNorm (optional gather) -> bf16
__global__ __launch_bounds__(256)
void ln_kernel(const float* __restrict__ in, const float* __restrict__ x,
               const int* __restrict__ sel,
               const float* __restrict__ g, const float* __restrict__ beta,
               bf16* __restrict__ out, int gather)
{
  int r = blockIdx.x;
  int tid = threadIdx.x;
  const float* src;
  if (gather) {
    int b = r >> 11, t = r & 2047;
    src = x + ((size_t)b * S_ + sel[b * KSEL + t]) * D_;
  } else {
    src = in + (size_t)r * D_;
  }
  float4 v = ((const float4*)src)[tid];
  float s = v.x + v.y + v.z + v.w;
  float sq = v.x * v.x + v.y * v.y + v.z * v.z + v.w * v.w;
  for (int off = 32; off; off >>= 1) { s += __shfl_down(s, off, 64); sq += __shfl_down(sq, off, 64); }
  __shared__ float wsA[4], wsB[4];
  if ((tid & 63) == 0) { wsA[tid >> 6] = s; wsB[tid >> 6] = sq; }
  __syncthreads();
  float stot = wsA[0] + wsA[1] + wsA[2] + wsA[3];
  float sqt  = wsB[0] + wsB[1] + wsB[2] + wsB[3];
  float mean = stot * (1.f / 1024.f);
  float var  = sqt * (1.f / 1024.f) - mean * mean;
  float rs = rsqrtf(var + 1e-5f);
  float4 gv = ((const float4*)g)[tid];
  float4 bv = ((const float4*)beta)[tid];
  bf16* o = out + (size_t)r * D_ + tid * 4;
  o[0] = __float2bfloat16((v.x - mean) * rs * gv.x + bv.x);
  o[1] = __float2bfloat16((v.y - mean) * rs * gv.y + bv.y);
  o[2] = __float2bfloat16((v.z - mean) * rs * gv.z + bv.z);
  o[3] = __float2bfloat16((v.w - mean) * rs * gv.w + bv.w);
}

// ---------------------------------------------------------------- 4) weight cast+transpose fp32[K][N] -> bf16[N][K]
__global__ __launch_bounds__(256)
void wtrans(const float* __restrict__ in, bf16* __restrict__ out, int K, int N)
{
  __shared__ float tile[32][33];
  int n0 = blockIdx.x * 32, k0 = blockIdx.y * 32;
  int r = threadIdx.x >> 5, c = threadIdx.x & 31;
#pragma unroll
  for (int i = 0; i < 4; ++i)
    tile[r + 8 * i][c] = in[(size_t)(k0 + r + 8 * i) * N + n0 + c];
  __syncthreads();
#pragma unroll
  for (int i = 0; i < 4; ++i)
    out[(size_t)(n0 + r + 8 * i) * K + k0 + c] = __float2bfloat16(tile[c][r + 8 * i]);
}

// ---------------------------------------------------------------- 5) V transpose: qkv[t][2048+h*64+d] -> vt[bh][d][t]
__global__ __launch_bounds__(256)
void vt_transpose(const bf16* __restrict__ qkv, bf16* __restrict__ vt)
{
  __shared__ bf16 tile[32][33];
  int bh = blockIdx.z;
  int d0 = blockIdx.y * 32;
  int t0 = blockIdx.x * 32;
  int b = bh >> 4, h = bh & 15;
  int r = threadIdx.x >> 5, c = threadIdx.x & 31;
#pragma unroll
  for (int i = 0; i < 4; ++i) {
    int t = t0 + r + 8 * i;
    tile[r + 8 * i][c] = qkv[(size_t)(b * KSEL + t) * 3072 + 2048 + h * 64 + d0 + c];
  }
  __syncthreads();
#pragma unroll
  for (int i = 0; i < 4; ++i) {
    int d = d0 + r + 8 * i;
    vt[((size_t)bh * 64 + d) * KSEL + t0 + c] = tile[c][r + 8 * i];
  }
}

// ---------------------------------------------------------------- 6) 256x256 8-phase GEMM (T3+T4+T5), C = A * Bt^T
// BM=BN=256, BK=64, 512 threads = 8 waves (2M x 4N), per-wave 128x64 output.
// LDS 128 KB: [buf2][A/B][khalf2][128x64] -- each half-tile is 256 rows x 32 k,
// packed as pseudo-row R=r>>1, col c=(r&1)*32+k', groups of 8 elems XOR-swizzled
// g' = g ^ (R&7) (same conflict-free family as the 128-tile kernel; staging
// source is inverse-swizzled per-lane, LDS dst linear -- rule 21).
// Per K-tile 4 phases = (khalf, ngroup): {ds_reads, stage 1 half-tile, barrier,
// lgkmcnt(0)+sched_barrier, setprio(1), 16 MFMA, setprio(0), [vmcnt], barrier}.
// Stage slots rotate one phase after each half's last read; vmcnt(6) at ph4/ph8
// keeps 3 half-tiles in flight (drain arithmetic verified for prologue/steady/tail).
// EPI 0: store bf16 (QKV). EPI 2: store bf16 gelu (FFN1).
#define STA(TILE, KH)                                                           \
  do { int kc_ = (TILE) * 64 + (KH) * 32 + kp;                                  \
    load_lds16(A + (size_t)(bm + sr0) * K + kc_, &lds[(TILE) & 1][0][KH][wid * 1024]);        \
    load_lds16(A + (size_t)(bm + sr1) * K + kc_, &lds[(TILE) & 1][0][KH][wid * 1024 + 512]);  \
  } while (0)
#define STB(TILE, KH)                                                           \
  do { int kc_ = (TILE) * 64 + (KH) * 32 + kp;                                  \
    load_lds16(Bt + (size_t)(bn + sr0) * K + kc_, &lds[(TILE) & 1][1][KH][wid * 1024]);       \
    load_lds16(Bt + (size_t)(bn + sr1) * K + kc_, &lds[(TILE) & 1][1][KH][wid * 1024 + 512]); \
  } while (0)

#define GPH(BSEL, KH, NG, STAGE_STMT, WAIT_STMT)                                \
  do {                                                                          \
    if (NG == 0) {                                                              \
      _Pragma("unroll")                                                         \
      for (int mt = 0; mt < 8; ++mt) {                                          \
        int r_ = wm * 128 + mt * 16 + l15;                                      \
        int R_ = r_ >> 1;                                                       \
        int gp_ = (((r_ & 1) << 2) + quad) ^ (R_ & 7);                          \
        af[mt] = *(const short8*)&lds[BSEL][0][KH][R_ * 64 + gp_ * 8];          \
      }                                                                         \
    }                                                                           \
    short8 bfr0, bfr1;                                                          \
    {                                                                           \
      int rb_ = wn * 64 + (NG * 2) * 16 + l15;                                  \
      int Rb_ = rb_ >> 1;                                                       \
      int gpb_ = (((rb_ & 1) << 2) + quad) ^ (Rb_ & 7);                         \
      bfr0 = *(const short8*)&lds[BSEL][1][KH][Rb_ * 64 + gpb_ * 8];            \
      int rc_ = rb_ + 16;                                                       \
      int Rc_ = rc_ >> 1;                                                       \
      int gpc_ = (((rc_ & 1) << 2) + quad) ^ (Rc_ & 7);                         \
      bfr1 = *(const short8*)&lds[BSEL][1][KH][Rc_ * 64 + gpc_ * 8];            \
    }                                                                           \
    STAGE_STMT;                                                                 \
    __builtin_amdgcn_s_barrier();                                               \
    asm volatile("s_waitcnt lgkmcnt(0)" ::: "memory");                          \
    __builtin_amdgcn_sched_barrier(0);                                          \
    __builtin_amdgcn_s_setprio(1);                                              \
    _Pragma("unroll")                                                           \
    for (int mt = 0; mt < 8; ++mt) {                                            \
      acc[mt][NG * 2]     = __builtin_amdgcn_mfma_f32_16x16x32_bf16(af[mt], bfr0, acc[mt][NG * 2], 0, 0, 0);     \
      acc[mt][NG * 2 + 1] = __builtin_amdgcn_mfma_f32_16x16x32_bf16(af[mt], bfr1, acc[mt][NG * 2 + 1], 0, 0, 0); \
    }                                                                           \
    __builtin_amdgcn_s_setprio(0);                                              \
    WAIT_STMT;                                                                  \
    __builtin_amdgcn_s_barrier();                                               \
  } while (0)

template<int EPI>
__global__ __launch_bounds__(512, 2)
void gemm256(const bf16* __restrict__ A, const bf16* __restrict__ Bt,
             bf16* __restrict__ Cb, int M, int N, int K)
{
  __shared__ bf16 lds[2][2][2][128 * 64];   // 128 KB
  const int tid = threadIdx.x;
  const int wid = tid >> 6;
  const int lane = tid & 63;
  const int l15 = lane & 15;
  const int quad = lane >> 4;
  const int wm = wid >> 2, wn = wid & 3;    // 2 x 4 waves
  const int bm = blockIdx.x * 256;
  const int bn = blockIdx.y * 256;

  // staging per-thread constants: inst i covers pseudo-rows (wid*2+i)*8..+8
  const int sgv = (lane & 7) ^ (lane >> 3);            // content group g at this lane's slot
  const int sr0 = wid * 32 + (lane >> 3) * 2 + (sgv >> 2);   // real row, inst 0
  const int sr1 = sr0 + 16;                                   // real row, inst 1
  const int kp  = (sgv & 3) * 8;                              // k offset within half

  f32x4 acc[8][4] = {};
  short8 af[8];

  const int NI = K >> 7;   // K/128 iterations, 2 K-tiles each (K multiple of 128, NI>=2)

  // prologue: tile0 fully + tile1 {A-kh0, B-kh0, A-kh1} = 7 half-tiles (14 loads)
  STA(0, 0); STB(0, 0); STA(0, 1); STB(0, 1);
  STA(1, 0); STB(1, 0); STA(1, 1);
  wait_vm6();                       // drain tile0's 8 loads; 6 in flight
  __builtin_amdgcn_s_barrier();

  for (int J = 0; J < NI; ++J) {
    const bool more = (J < NI - 1);
    const int t2 = 2 * J + 2, t3 = 2 * J + 3;
    GPH(0, 0, 0, STB(2 * J + 1, 1), ((void)0));                              // ph1
    GPH(0, 0, 1, if (more) STA(t2, 0), ((void)0));                           // ph2
    GPH(0, 1, 0, if (more) STB(t2, 0), ((void)0));                           // ph3
    GPH(0, 1, 1, if (more) STA(t2, 1), if (more) wait_vm6(); else wait_vm0()); // ph4
    GPH(1, 0, 0, if (more) STB(t2, 1), ((void)0));                           // ph5
    GPH(1, 0, 1, if (more) STA(t3, 0), ((void)0));                           // ph6
    GPH(1, 1, 0, if (more) STB(t3, 0), ((void)0));                           // ph7
    GPH(1, 1, 1, if (more) STA(t3, 1), if (more) wait_vm6());                // ph8
  }

#pragma unroll
  for (int mt = 0; mt < 8; ++mt) {
#pragma unroll
    for (int r = 0; r < 4; ++r) {
      int gm = bm + wm * 128 + mt * 16 + quad * 4 + r;
#pragma unroll
      for (int nt = 0; nt < 4; ++nt) {
        int gn = bn + wn * 64 + nt * 16 + l15;
        float v = acc[mt][nt][r];
        if (EPI == 0) {
          Cb[(size_t)gm * N + gn] = __float2bfloat16(v);
        } else {
          float u = v;
          float cc = 0.7978845608028654f * (u + 0.044715f * u * u * u);
          float e = __expf(2.f * cc);
          float th = 1.f - 2.f / (e + 1.f);
          Cb[(size_t)gm * N + gn] = __float2bfloat16(0.5f * u * (1.f + th));
        }
      }
    }
  }
}

// ---------------------------------------------------------------- 6b) 128-tile GEMM + fused epilogues (o-proj, FFN2)
// EPI 1: Cf = gather(x) + acc  (o-proj residual, fp32)
// EPI 3: out[b,sel,n] += rw*(x1 + acc)  (FFN2 + final scatter; each (gm,gn)
//        owned by exactly one thread -- sel entries distinct -- plain RMW)
template<int EPI, int TN>
__global__ __launch_bounds__(256)
void gemm_bt(const bf16* __restrict__ A, const bf16* __restrict__ Bt,
             float* __restrict__ Cf, bf16* __restrict__ Cb,
             int M, int N, int K,
             const float* __restrict__ xin, const int* __restrict__ sel,
             const float* __restrict__ rw, const float* __restrict__ x1,
             float* __restrict__ outp)
{
  constexpr int NT = TN / 32;
  constexpr int WN = TN / 2;
  __shared__ bf16 As[128 * 64];
  __shared__ bf16 Bs[TN * 64];
  const int tid = threadIdx.x;
  const int wid = tid >> 6;
  const int lane = tid & 63;
  const int l15 = lane & 15;
  const int quad = lane >> 4;
  const int wm = wid >> 1, wn = wid & 1;
  const int bm = blockIdx.x * 128;
  const int bn = blockIdx.y * TN;

  const int srow = lane >> 3;
  const int sgrp = (lane & 7) ^ srow;

  f32x4 acc[4][NT] = {};

  for (int k0 = 0; k0 < K; k0 += 64) {
#pragma unroll
    for (int c2 = 0; c2 < 4; ++c2) {
      int c = wid * 4 + c2;
      const bf16* ga = A + (size_t)(bm + c * 8 + srow) * K + (k0 + sgrp * 8);
      load_lds16(ga, &As[c * 512]);
    }
#pragma unroll
    for (int c2 = 0; c2 < TN / 32; ++c2) {
      int c = wid * (TN / 32) + c2;
      const bf16* gb = Bt + (size_t)(bn + c * 8 + srow) * K + (k0 + sgrp * 8);
      load_lds16(gb, &Bs[c * 512]);
    }
    __syncthreads();
#pragma unroll
    for (int ks = 0; ks < 2; ++ks) {
      short8 af[4], bfv[NT];
#pragma unroll
      for (int mt = 0; mt < 4; ++mt) {
        int row = wm * 64 + mt * 16 + l15;
        int cg = (ks * 4 + quad) ^ (row & 7);
        af[mt] = *(const short8*)&As[row * 64 + cg * 8];
      }
#pragma unroll
      for (int nt = 0; nt < NT; ++nt) {
        int row = wn * WN + nt * 16 + l15;
        int cg = (ks * 4 + quad) ^ (row & 7);
        bfv[nt] = *(const short8*)&Bs[row * 64 + cg * 8];
      }
#pragma unroll
      for (int mt = 0; mt < 4; ++mt)
#pragma unroll
        for (int nt = 0; nt < NT; ++nt)
          acc[mt][nt] = __builtin_amdgcn_mfma_f32_16x16x32_bf16(af[mt], bfv[nt], acc[mt][nt], 0, 0, 0);
    }
    __syncthreads();
  }

#pragma unroll
  for (int mt = 0; mt < 4; ++mt) {
#pragma unroll
    for (int r = 0; r < 4; ++r) {
      int gm = bm + wm * 64 + mt * 16 + quad * 4 + r;
      int bb = gm >> 11, tt = gm & 2047;
      int sr = 0; float rwv = 0.f;
      if (EPI == 1 || EPI == 3) sr = sel[bb * KSEL + tt];
      if (EPI == 3) rwv = rw[bb * KSEL + tt];
#pragma unroll
      for (int nt = 0; nt < NT; ++nt) {
        int gn = bn + wn * WN + nt * 16 + l15;
        float v = acc[mt][nt][r];
        if (EPI == 1) {
          float xv = xin[((size_t)bb * S_ + sr) * D_ + gn];
          Cf[(size_t)gm * N + gn] = xv + v;
        } else {
          float v2 = rwv * (x1[(size_t)gm * D_ + gn] + v);
          outp[((size_t)bb * S_ + sr) * D_ + gn] += v2;
        }
      }
    }
  }
}

// ---------------------------------------------------------------- 7) flash attention, swapped-operand + in-register P
__global__ __launch_bounds__(256)
void flash_kernel(const bf16* __restrict__ qkv, const bf16* __restrict__ vt,
                  bf16* __restrict__ attn_o)
{
  __shared__ bf16 Ks[128 * 64];        // [token][dh]   16 KB
  __shared__ bf16 Vs[64 * 128];        // [dh][token]   16 KB
  int qt = blockIdx.x, h = blockIdx.y, b = blockIdx.z;
  int tid = threadIdx.x, wid = tid >> 6, lane = tid & 63;
  int l15 = lane & 15, quad = lane >> 4;
  int q0 = qt * 128 + wid * 32;

  const int srowK = lane >> 3, sgK = lane & 7;
  const int srowV = lane >> 4, sgV = lane & 15;

  short8 qf[2][2];
#pragma unroll
  for (int mt = 0; mt < 2; ++mt)
#pragma unroll
    for (int ks = 0; ks < 2; ++ks) {
      const bf16* p = qkv + (size_t)(b * KSEL + q0 + mt * 16 + l15) * 3072 + h * 64 + ks * 32 + quad * 8;
      qf[mt][ks] = scale8(*(const short8*)p, 0.125f * 1.44269504f);
    }

  f32x4 acc_ot[2][4] = {};
  float lsum[2] = {};

  const bf16* Vg = vt + (size_t)(b * NH + h) * 64 * KSEL;

  for (int kt = 0; kt < KSEL / 128; ++kt) {
    int tok0 = b * KSEL + kt * 128;
    __syncthreads();
#pragma unroll
    for (int i = 0; i < 4; ++i) {
      int c = wid * 4 + i;
      const bf16* ga = qkv + (size_t)(tok0 + c * 8 + srowK) * 3072 + 1024 + h * 64 + ((sgK ^ srowK) * 8);
      load_lds16(ga, &Ks[c * 512]);
      int vr = c * 4 + srowV;
      const bf16* gv = Vg + (size_t)vr * KSEL + kt * 128 + ((sgV ^ (vr & 7)) * 8);
      load_lds16(gv, &Vs[c * 512]);
    }
    __syncthreads();

#pragma unroll
    for (int ks4 = 0; ks4 < 4; ++ks4) {
      f32x4 s[2][2] = {};
#pragma unroll
      for (int u = 0; u < 2; ++u) {
        int row = (ks4 * 2 + u) * 16 + l15;
#pragma unroll
        for (int ks = 0; ks < 2; ++ks) {
          int g = (ks * 4 + quad) ^ (row & 7);
          short8 kf = *(const short8*)&Ks[row * 64 + g * 8];
#pragma unroll
          for (int mt = 0; mt < 2; ++mt)
            s[mt][u] = __builtin_amdgcn_mfma_f32_16x16x32_bf16(kf, qf[mt][ks], s[mt][u], 0, 0, 0);
        }
      }
      short8 pfrag[2];
#pragma unroll
      for (int mt = 0; mt < 2; ++mt) {
        float pA[4], pB[4];
#pragma unroll
        for (int r = 0; r < 4; ++r) {
          pA[r] = __builtin_amdgcn_exp2f(s[mt][0][r]);
          pB[r] = __builtin_amdgcn_exp2f(s[mt][1][r]);
          lsum[mt] += pA[r] + pB[r];
        }
        unsigned A0 = cvt_pk_bf16(pA[0], pA[1]);
        unsigned A1 = cvt_pk_bf16(pA[2], pA[3]);
        unsigned B0 = cvt_pk_bf16(pB[0], pB[1]);
        unsigned B1 = cvt_pk_bf16(pB[2], pB[3]);
        pl32_swap(A0, B0); pl16_swap(A0, B0);
        pl32_swap(A1, B1); pl16_swap(A1, B1);
        uint4v w; w[0] = A0; w[1] = A1; w[2] = B0; w[3] = B1;
        pfrag[mt] = __builtin_bit_cast(short8, w);
      }
#pragma unroll
      for (int dt = 0; dt < 4; ++dt) {
        int row = dt * 16 + l15;
        int g = (ks4 * 4 + quad) ^ (row & 7);
        short8 vf = *(const short8*)&Vs[row * 128 + g * 8];
#pragma unroll
        for (int mt = 0; mt < 2; ++mt)
          acc_ot[mt][dt] = __builtin_amdgcn_mfma_f32_16x16x32_bf16(vf, pfrag[mt], acc_ot[mt][dt], 0, 0, 0);
      }
    }
  }
#pragma unroll
  for (int mt = 0; mt < 2; ++mt) {
    float l = lsum[mt];
    l += __shfl_xor(l, 16, 64);
    l += __shfl_xor(l, 32, 64);
    float invl = 1.0f / l;
#pragma unroll
    for (int dt = 0; dt < 4; ++dt) {
      ushort4v o;
#pragma unroll
      for (int r = 0; r < 4; ++r) {
        bf16 t = __float2bfloat16(acc_ot[mt][dt][r] * invl);
        unsigned short us;
        __builtin_memcpy(&us, &t, 2);
        o[r] = us;
      }
      *(ushort4v*)(attn_o + (size_t)(b * KSEL + q0 + mt * 16 + l15) * D_ + h * 64 + dt * 16 + quad * 4) = o;
    }
  }
}

// ---------------------------------------------------------------- launch
extern "C" void kernel_launch(void* const* d_in, const int* in_sizes, int n_in,
                              void* d_out, int out_size, void* d_ws, size_t ws_size,
                              hipStream_t stream)
{
  const float* x      = (const float*)d_in[0];
  const float* router = (const float*)d_in[1];
  const float* ln1g   = (const float*)d_in[2];
  const float* ln1b   = (const float*)d_in[3];
  const float* ln2g   = (const float*)d_in[4];
  const float* ln2b   = (const float*)d_in[5];
  const float* wqkv   = (const float*)d_in[6];
  const float* wo     = (const float*)d_in[7];
  const float* w1     = (const float*)d_in[8];
  const float* w2     = (const float*)d_in[9];
  float* out = (float*)d_out;
  char* ws = (char*)d_ws;

  float* logits = (float*)(ws + 0);                 // 64 KB
  int*   sel    = (int*)  (ws + 65536);             // 32 KB
  float* rw     = (float*)(ws + 98304);             // 32 KB
  bf16* wqkvT   = (bf16*) (ws + 131072);            // 6 MB   [3072][1024]
  bf16* woT     = (bf16*) (ws + 6422528);           // 2 MB   [1024][1024]
  bf16* w1T     = (bf16*) (ws + 8519680);           // 8 MB   [4096][1024]
  bf16* w2T     = (bf16*) (ws + 16908288);          // 8 MB   [1024][4096]
  bf16* regA    = (bf16*) (ws + 25296896);          // 16 MB  h1 / attn_o / h2
  bf16* regB    = (bf16*) (ws + 42074112);          // 64 MB  qkv(48)+vt(16) then ffn_h
  bf16* vtb     = (bf16*) (ws + 42074112 + 50331648);
  float* x1     = (float*)(ws + 109182976);         // 32 MB

  copy_router<<<dim3(S_, B_), 256, 0, stream>>>(x, router, out, logits);
  topk_kernel<<<B_, 1024, 0, stream>>>(logits, sel, rw);

  wtrans<<<dim3(3072 / 32, 1024 / 32), 256, 0, stream>>>(wqkv, wqkvT, 1024, 3072);
  wtrans<<<dim3(1024 / 32, 1024 / 32), 256, 0, stream>>>(wo,   woT,   1024, 1024);
  wtrans<<<dim3(4096 / 32, 1024 / 32), 256, 0, stream>>>(w1,   w1T,   1024, 4096);
  wtrans<<<dim3(1024 / 32, 4096 / 32), 256, 0, stream>>>(w2,   w2T,   4096, 1024);

  ln_kernel<<<B_ * KSEL, 256, 0, stream>>>(nullptr, x, sel, ln1g, ln1b, regA, 1);

  // QKV: [8192x1024] * [3072x1024]^T -> bf16 [8192][3072]  (8-phase 256^2)
  gemm256<0><<<dim3(32, 12), 512, 0, stream>>>(regA, wqkvT, regB, 8192, 3072, 1024);
  vt_transpose<<<dim3(KSEL / 32, 2, B_ * NH), 256, 0, stream>>>(regB, vtb);
  flash_kernel<<<dim3(KSEL / 128, NH, B_), 256, 0, stream>>>(regB, vtb, regA);

  // o-proj + gather residual: x1 = gather(x) + attn_o * wo
  gemm_bt<1, 128><<<dim3(64, 8), 256, 0, stream>>>(regA, woT, x1, nullptr, 8192, 1024, 1024,
                                                   x, sel, nullptr, nullptr, nullptr);
  ln_kernel<<<B_ * KSEL, 256, 0, stream>>>(x1, nullptr, nullptr, ln2g, ln2b, regA, 0);
  // FFN1 + gelu -> bf16 [8192][4096]  (8-phase 256^2)
  gemm256<2><<<dim3(32, 16), 512, 0, stream>>>(regA, w1T, regB, 8192, 4096, 1024);
  // FFN2 + scatter: out[b,sel,:] += rw * (x1 + acc)
  gemm_bt<3, 128><<<dim3(64, 8), 256, 0, stream>>>(regB, w2T, nullptr, nullptr, 8192, 1024, 4096,
                                                   nullptr, sel, rw, x1, out);
}

// Round 5
// 612.455 us; speedup vs baseline: 1.1364x; 1.0458x over previous
//
#include <hip/hip_runtime.h>
#include <hip/hip_bf16.h>
#include <stdint.h>

typedef __hip_bfloat16 bf16;
typedef __attribute__((ext_vector_type(8))) short short8;   // 8 bf16 = 4 VGPRs (MFMA A/B frag)
typedef __attribute__((ext_vector_type(4))) float f32x4;    // MFMA C/D frag
typedef __attribute__((ext_vector_type(2))) unsigned uint2v;
typedef __attribute__((ext_vector_type(4))) unsigned uint4v;
typedef __attribute__((ext_vector_type(4))) unsigned short ushort4v;

#define B_   4
#define S_   4096
#define D_   1024
#define KSEL 2048
#define DFF  4096
#define NH   16
#define DH   64

// ---------------------------------------------------------------- helpers
static __device__ __forceinline__ void load_lds16(const void* g, void* l) {
  // async global->LDS, 16B per lane, dst = wave-uniform base + lane*16
  __builtin_amdgcn_global_load_lds((const __attribute__((address_space(1))) void*)g,
                                   (__attribute__((address_space(3))) void*)l,
                                   16, 0, 0);
}

static __device__ __forceinline__ short8 scale8(short8 v, float s) {
  short8 r;
#pragma unroll
  for (int i = 0; i < 8; ++i) {
    unsigned u = ((unsigned)(unsigned short)v[i]) << 16;
    float f = __uint_as_float(u) * s;
    bf16 o = __float2bfloat16(f);
    short t;
    __builtin_memcpy(&t, &o, 2);
    r[i] = t;
  }
  return r;
}

static __device__ __forceinline__ unsigned cvt_pk_bf16(float lo, float hi) {
  unsigned r;
  asm("v_cvt_pk_bf16_f32 %0, %1, %2" : "=v"(r) : "v"(lo), "v"(hi));
  return r;
}

static __device__ __forceinline__ void pl32_swap(unsigned &a, unsigned &b) {
#if __has_builtin(__builtin_amdgcn_permlane32_swap)
  uint2v r = __builtin_amdgcn_permlane32_swap(a, b, false, false);
  a = r[0]; b = r[1];
#else
  asm("v_permlane32_swap_b32 %0, %1" : "+v"(a), "+v"(b));
#endif
}

static __device__ __forceinline__ void pl16_swap(unsigned &a, unsigned &b) {
#if __has_builtin(__builtin_amdgcn_permlane16_swap)
  uint2v r = __builtin_amdgcn_permlane16_swap(a, b, false, false);
  a = r[0]; b = r[1];
#else
  asm("v_permlane16_swap_b32 %0, %1" : "+v"(a), "+v"(b));
#endif
}

// ---------------------------------------------------------------- 1) copy x -> out, logits = x @ router_w
__global__ __launch_bounds__(256)
void copy_router(const float* __restrict__ x, const float* __restrict__ rwts,
                 float* __restrict__ out, float* __restrict__ logits)
{
  int s = blockIdx.x, b = blockIdx.y;
  int tid = threadIdx.x;
  const float4* row = (const float4*)(x + ((size_t)b * S_ + s) * D_);
  float4 v = row[tid];
  ((float4*)(out + ((size_t)b * S_ + s) * D_))[tid] = v;
  float4 rv = ((const float4*)rwts)[tid];
  float p = v.x * rv.x + v.y * rv.y + v.z * rv.z + v.w * rv.w;
  for (int off = 32; off; off >>= 1) p += __shfl_down(p, off, 64);
  __shared__ float wsum[4];
  if ((tid & 63) == 0) wsum[tid >> 6] = p;
  __syncthreads();
  if (tid == 0) logits[(size_t)b * S_ + s] = wsum[0] + wsum[1] + wsum[2] + wsum[3];
}

// ---------------------------------------------------------------- 2) per-batch top-K: binary-search threshold select
// T = max u32 key t with count(key >= t) >= KSEL (keys monotone-encoded floats,
// held in registers). Selected set = {key > T} + first (KSEL - n_gt) elements
// with key == T in index order -- identical to stable top_k semantics.
__global__ __launch_bounds__(1024)
void topk_kernel(const float* __restrict__ logits,
                 int* __restrict__ sel, float* __restrict__ rw)
{
  __shared__ int   wredi[16];
  __shared__ float wredf[16];
  __shared__ int   woff[17];

  int b = blockIdx.x, tid = threadIdx.x;
  int lane = tid & 63, wv = tid >> 6;
  const float* L = logits + (size_t)b * S_;
  int base = tid * 4;
  float4 v = ((const float4*)L)[tid];
  // monotone key: ascending key order == ascending float order
  unsigned k0, k1, k2, k3;
  {
    unsigned u;
    u = __float_as_uint(v.x); k0 = (u & 0x80000000u) ? ~u : (u | 0x80000000u);
    u = __float_as_uint(v.y); k1 = (u & 0x80000000u) ? ~u : (u | 0x80000000u);
    u = __float_as_uint(v.z); k2 = (u & 0x80000000u) ? ~u : (u | 0x80000000u);
    u = __float_as_uint(v.w); k3 = (u & 0x80000000u) ? ~u : (u | 0x80000000u);
  }
  // block max (softmax shift; max logit value == max selected value)
  float mx = fmaxf(fmaxf(v.x, v.y), fmaxf(v.z, v.w));
  for (int off = 32; off; off >>= 1) mx = fmaxf(mx, __shfl_xor(mx, off, 64));
  if (lane == 0) wredf[wv] = mx;
  __syncthreads();
  float m = wredf[0];
  for (int w = 1; w < 16; ++w) m = fmaxf(m, wredf[w]);

  // greedy bit-by-bit threshold search (count_ge monotone non-increasing)
  unsigned T = 0;
  for (int bit = 31; bit >= 0; --bit) {
    unsigned cand = T | (1u << bit);
    int c = (int)(k0 >= cand) + (int)(k1 >= cand) + (int)(k2 >= cand) + (int)(k3 >= cand);
    for (int off = 32; off; off >>= 1) c += __shfl_xor(c, off, 64);
    __syncthreads();
    if (lane == 0) wredi[wv] = c;
    __syncthreads();
    int tot = 0;
    for (int w = 0; w < 16; ++w) tot += wredi[w];
    if (tot >= KSEL) T = cand;
  }
  // strictly-greater count
  int cg = (int)(k0 > T) + (int)(k1 > T) + (int)(k2 > T) + (int)(k3 > T);
  for (int off = 32; off; off >>= 1) cg += __shfl_xor(cg, off, 64);
  __syncthreads();
  if (lane == 0) wredi[wv] = cg;
  __syncthreads();
  int n_gt = 0;
  for (int w = 0; w < 16; ++w) n_gt += wredi[w];
  int need = KSEL - n_gt;
  // exclusive prefix of eq-flags (index order) to rank tie elements
  int e0 = (k0 == T), e1 = (k1 == T), e2 = (k2 == T), e3 = (k3 == T);
  int esum = e0 + e1 + e2 + e3;
  int eincl = esum;
  for (int off = 1; off < 64; off <<= 1) { int t = __shfl_up(eincl, off, 64); if (lane >= off) eincl += t; }
  __syncthreads();
  if (lane == 63) wredi[wv] = eincl;
  __syncthreads();
  int ebase = 0;
  for (int w = 0; w < wv; ++w) ebase += wredi[w];
  int ep = ebase + eincl - esum;
  int f0 = (k0 > T) || (e0 && ep < need); ep += e0;
  int f1 = (k1 > T) || (e1 && ep < need); ep += e1;
  int f2 = (k2 > T) || (e2 && ep < need); ep += e2;
  int f3 = (k3 > T) || (e3 && ep < need); ep += e3;
  // softmax denominator over selected
  float part = 0.f;
  if (f0) part += __expf(v.x - m);
  if (f1) part += __expf(v.y - m);
  if (f2) part += __expf(v.z - m);
  if (f3) part += __expf(v.w - m);
  for (int off = 32; off; off >>= 1) part += __shfl_xor(part, off, 64);
  __syncthreads();
  if (lane == 0) wredf[wv] = part;
  __syncthreads();
  float tot = 0.f;
  for (int w = 0; w < 16; ++w) tot += wredf[w];
  float inv = 1.0f / tot;
  // compaction: ascending-index positions via prefix scan
  int mysum = f0 + f1 + f2 + f3;
  int incl = mysum;
  for (int off = 1; off < 64; off <<= 1) { int t = __shfl_up(incl, off, 64); if (lane >= off) incl += t; }
  __syncthreads();
  if (lane == 63) wredi[wv] = incl;
  __syncthreads();
  if (tid == 0) { int s = 0; for (int w = 0; w < 16; ++w) { woff[w] = s; s += wredi[w]; } woff[16] = s; }
  __syncthreads();
  int p = woff[wv] + incl - mysum;
  float vv[4] = { v.x, v.y, v.z, v.w };
  int ff[4] = { f0, f1, f2, f3 };
  for (int q = 0; q < 4; ++q) {
    if (ff[q]) {
      sel[b * KSEL + p] = base + q;
      rw[b * KSEL + p] = __expf(vv[q] - m) * inv;
      p++;
    }
  }
}

// ---------------------------------------------------------------- 3) LayerNorm (optional gather) -> bf16
__global__ __launch_bounds__(256)
void ln_kernel(const float* __restrict__ in, const float* __restrict__ x,
               const int* __restrict__ sel,
               const float* __restrict__ g, const float* __restrict__ beta,
               bf16* __restrict__ out, int gather)
{
  int r = blockIdx.x;
  int tid = threadIdx.x;
  const float* src;
  if (gather) {
    int b = r >> 11, t = r & 2047;
    src = x + ((size_t)b * S_ + sel[b * KSEL + t]) * D_;
  } else {
    src = in + (size_t)r * D_;
  }
  float4 v = ((const float4*)src)[tid];
  float s = v.x + v.y + v.z + v.w;
  float sq = v.x * v.x + v.y * v.y + v.z * v.z + v.w * v.w;
  for (int off = 32; off; off >>= 1) { s += __shfl_down(s, off, 64); sq += __shfl_down(sq, off, 64); }
  __shared__ float wsA[4], wsB[4];
  if ((tid & 63) == 0) { wsA[tid >> 6] = s; wsB[tid >> 6] = sq; }
  __syncthreads();
  float stot = wsA[0] + wsA[1] + wsA[2] + wsA[3];
  float sqt  = wsB[0] + wsB[1] + wsB[2] + wsB[3];
  float mean = stot * (1.f / 1024.f);
  float var  = sqt * (1.f / 1024.f) - mean * mean;
  float rs = rsqrtf(var + 1e-5f);
  float4 gv = ((const float4*)g)[tid];
  float4 bv = ((const float4*)beta)[tid];
  bf16* o = out + (size_t)r * D_ + tid * 4;
  o[0] = __float2bfloat16((v.x - mean) * rs * gv.x + bv.x);
  o[1] = __float2bfloat16((v.y - mean) * rs * gv.y + bv.y);
  o[2] = __float2bfloat16((v.z - mean) * rs * gv.z + bv.z);
  o[3] = __float2bfloat16((v.w - mean) * rs * gv.w + bv.w);
}

// ---------------------------------------------------------------- 4) weight cast+transpose fp32[K][N] -> bf16[N][K]
__global__ __launch_bounds__(256)
void wtrans(const float* __restrict__ in, bf16* __restrict__ out, int K, int N)
{
  __shared__ float tile[32][33];
  int n0 = blockIdx.x * 32, k0 = blockIdx.y * 32;
  int r = threadIdx.x >> 5, c = threadIdx.x & 31;
#pragma unroll
  for (int i = 0; i < 4; ++i)
    tile[r + 8 * i][c] = in[(size_t)(k0 + r + 8 * i) * N + n0 + c];
  __syncthreads();
#pragma unroll
  for (int i = 0; i < 4; ++i)
    out[(size_t)(n0 + r + 8 * i) * K + k0 + c] = __float2bfloat16(tile[c][r + 8 * i]);
}

// ---------------------------------------------------------------- 5) V transpose: qkv[t][2048+h*64+d] -> vt[bh][d][t]
__global__ __launch_bounds__(256)
void vt_transpose(const bf16* __restrict__ qkv, bf16* __restrict__ vt)
{
  __shared__ bf16 tile[32][33];
  int bh = blockIdx.z;
  int d0 = blockIdx.y * 32;
  int t0 = blockIdx.x * 32;
  int b = bh >> 4, h = bh & 15;
  int r = threadIdx.x >> 5, c = threadIdx.x & 31;
#pragma unroll
  for (int i = 0; i < 4; ++i) {
    int t = t0 + r + 8 * i;
    tile[r + 8 * i][c] = qkv[(size_t)(b * KSEL + t) * 3072 + 2048 + h * 64 + d0 + c];
  }
  __syncthreads();
#pragma unroll
  for (int i = 0; i < 4; ++i) {
    int d = d0 + r + 8 * i;
    vt[((size_t)bh * 64 + d) * KSEL + t0 + c] = tile[c][r + 8 * i];
  }
}

// ---------------------------------------------------------------- 6) GEMM C = A(bf16 MxK) * Bt(bf16 NxK)^T  + fused epilogues
// EPI 0: store bf16            (QKV)
// EPI 1: Cf = gather(x) + acc  (o-proj residual, fp32)
// EPI 2: store bf16 gelu(acc)  (FFN1)
// EPI 3: out[b,sel,n] += rw*(x1 + acc)  (FFN2 + final scatter; each (gm,gn)
//        owned by exactly one thread -- sel entries distinct -- plain RMW)
template<int EPI, int TN>
__global__ __launch_bounds__(256)
void gemm_bt(const bf16* __restrict__ A, const bf16* __restrict__ Bt,
             float* __restrict__ Cf, bf16* __restrict__ Cb,
             int M, int N, int K,
             const float* __restrict__ xin, const int* __restrict__ sel,
             const float* __restrict__ rw, const float* __restrict__ x1,
             float* __restrict__ outp)
{
  constexpr int NT = TN / 32;
  constexpr int WN = TN / 2;
  __shared__ bf16 As[128 * 64];
  __shared__ bf16 Bs[TN * 64];
  const int tid = threadIdx.x;
  const int wid = tid >> 6;
  const int lane = tid & 63;
  const int l15 = lane & 15;
  const int quad = lane >> 4;
  const int wm = wid >> 1, wn = wid & 1;
  const int bm = blockIdx.x * 128;
  const int bn = blockIdx.y * TN;

  const int srow = lane >> 3;
  const int sgrp = (lane & 7) ^ srow;

  f32x4 acc[4][NT] = {};

  for (int k0 = 0; k0 < K; k0 += 64) {
#pragma unroll
    for (int c2 = 0; c2 < 4; ++c2) {
      int c = wid * 4 + c2;
      const bf16* ga = A + (size_t)(bm + c * 8 + srow) * K + (k0 + sgrp * 8);
      load_lds16(ga, &As[c * 512]);
    }
#pragma unroll
    for (int c2 = 0; c2 < TN / 32; ++c2) {
      int c = wid * (TN / 32) + c2;
      const bf16* gb = Bt + (size_t)(bn + c * 8 + srow) * K + (k0 + sgrp * 8);
      load_lds16(gb, &Bs[c * 512]);
    }
    __syncthreads();
#pragma unroll
    for (int ks = 0; ks < 2; ++ks) {
      short8 af[4], bfv[NT];
#pragma unroll
      for (int mt = 0; mt < 4; ++mt) {
        int row = wm * 64 + mt * 16 + l15;
        int cg = (ks * 4 + quad) ^ (row & 7);
        af[mt] = *(const short8*)&As[row * 64 + cg * 8];
      }
#pragma unroll
      for (int nt = 0; nt < NT; ++nt) {
        int row = wn * WN + nt * 16 + l15;
        int cg = (ks * 4 + quad) ^ (row & 7);
        bfv[nt] = *(const short8*)&Bs[row * 64 + cg * 8];
      }
#pragma unroll
      for (int mt = 0; mt < 4; ++mt)
#pragma unroll
        for (int nt = 0; nt < NT; ++nt)
          acc[mt][nt] = __builtin_amdgcn_mfma_f32_16x16x32_bf16(af[mt], bfv[nt], acc[mt][nt], 0, 0, 0);
    }
    __syncthreads();
  }

#pragma unroll
  for (int mt = 0; mt < 4; ++mt) {
#pragma unroll
    for (int r = 0; r < 4; ++r) {
      int gm = bm + wm * 64 + mt * 16 + quad * 4 + r;
      int bb = gm >> 11, tt = gm & 2047;
      int sr = 0; float rwv = 0.f;
      if (EPI == 1 || EPI == 3) sr = sel[bb * KSEL + tt];
      if (EPI == 3) rwv = rw[bb * KSEL + tt];
#pragma unroll
      for (int nt = 0; nt < NT; ++nt) {
        int gn = bn + wn * WN + nt * 16 + l15;
        float v = acc[mt][nt][r];
        if (EPI == 0) {
          Cb[(size_t)gm * N + gn] = __float2bfloat16(v);
        } else if (EPI == 1) {
          float xv = xin[((size_t)bb * S_ + sr) * D_ + gn];
          Cf[(size_t)gm * N + gn] = xv + v;
        } else if (EPI == 2) {
          float u = v;
          float cc = 0.7978845608028654f * (u + 0.044715f * u * u * u);
          float e = __expf(2.f * cc);
          float th = 1.f - 2.f / (e + 1.f);
          Cb[(size_t)gm * N + gn] = __float2bfloat16(0.5f * u * (1.f + th));
        } else {
          float v2 = rwv * (x1[(size_t)gm * D_ + gn] + v);
          outp[((size_t)bb * S_ + sr) * D_ + gn] += v2;
        }
      }
    }
  }
}

// ---------------------------------------------------------------- 7) flash attention, swapped-operand + in-register P,
// double-buffered K/V staging (T14/T3-minimum): per tile, issue next tile's
// global_load_lds BEFORE compute; single __syncthreads (implicit vmcnt(0)
// drain) per tile. Load latency hides under ~600cyc of MFMA+softmax VALU.
// Write-after-read safe: buf staged at iter kt was last read at kt-1, sealed
// by that iteration's barrier.
__global__ __launch_bounds__(256)
void flash_kernel(const bf16* __restrict__ qkv, const bf16* __restrict__ vt,
                  bf16* __restrict__ attn_o)
{
  __shared__ bf16 Ks[2][128 * 64];     // [buf][token][dh]   32 KB
  __shared__ bf16 Vs[2][64 * 128];     // [buf][dh][token]   32 KB
  int qt = blockIdx.x, h = blockIdx.y, b = blockIdx.z;
  int tid = threadIdx.x, wid = tid >> 6, lane = tid & 63;
  int l15 = lane & 15, quad = lane >> 4;
  int q0 = qt * 128 + wid * 32;

  const int srowK = lane >> 3, sgK = lane & 7;
  const int srowV = lane >> 4, sgV = lane & 15;

  short8 qf[2][2];
#pragma unroll
  for (int mt = 0; mt < 2; ++mt)
#pragma unroll
    for (int ks = 0; ks < 2; ++ks) {
      const bf16* p = qkv + (size_t)(b * KSEL + q0 + mt * 16 + l15) * 3072 + h * 64 + ks * 32 + quad * 8;
      qf[mt][ks] = scale8(*(const short8*)p, 0.125f * 1.44269504f);
    }

  f32x4 acc_ot[2][4] = {};
  float lsum[2] = {};

  const bf16* Vg = vt + (size_t)(b * NH + h) * 64 * KSEL;

  // prologue: stage tile 0 into buf 0
  {
    int tok0 = b * KSEL;
#pragma unroll
    for (int i = 0; i < 4; ++i) {
      int c = wid * 4 + i;
      const bf16* ga = qkv + (size_t)(tok0 + c * 8 + srowK) * 3072 + 1024 + h * 64 + ((sgK ^ srowK) * 8);
      load_lds16(ga, &Ks[0][c * 512]);
      int vr = c * 4 + srowV;
      const bf16* gv = Vg + (size_t)vr * KSEL + ((sgV ^ (vr & 7)) * 8);
      load_lds16(gv, &Vs[0][c * 512]);
    }
  }
  __syncthreads();   // implicit vmcnt(0): tile 0 landed

  for (int kt = 0; kt < KSEL / 128; ++kt) {
    const int cur = kt & 1;
    // issue next tile's staging into the other buffer (hidden under compute)
    if (kt < KSEL / 128 - 1) {
      int tok0 = b * KSEL + (kt + 1) * 128;
#pragma unroll
      for (int i = 0; i < 4; ++i) {
        int c = wid * 4 + i;
        const bf16* ga = qkv + (size_t)(tok0 + c * 8 + srowK) * 3072 + 1024 + h * 64 + ((sgK ^ srowK) * 8);
        load_lds16(ga, &Ks[cur ^ 1][c * 512]);
        int vr = c * 4 + srowV;
        const bf16* gv = Vg + (size_t)vr * KSEL + (kt + 1) * 128 + ((sgV ^ (vr & 7)) * 8);
        load_lds16(gv, &Vs[cur ^ 1][c * 512]);
      }
    }

#pragma unroll
    for (int ks4 = 0; ks4 < 4; ++ks4) {
      f32x4 s[2][2] = {};
#pragma unroll
      for (int u = 0; u < 2; ++u) {
        int row = (ks4 * 2 + u) * 16 + l15;
#pragma unroll
        for (int ks = 0; ks < 2; ++ks) {
          int g = (ks * 4 + quad) ^ (row & 7);
          short8 kf = *(const short8*)&Ks[cur][row * 64 + g * 8];
#pragma unroll
          for (int mt = 0; mt < 2; ++mt)
            s[mt][u] = __builtin_amdgcn_mfma_f32_16x16x32_bf16(kf, qf[mt][ks], s[mt][u], 0, 0, 0);
        }
      }
      short8 pfrag[2];
#pragma unroll
      for (int mt = 0; mt < 2; ++mt) {
        float pA[4], pB[4];
#pragma unroll
        for (int r = 0; r < 4; ++r) {
          pA[r] = __builtin_amdgcn_exp2f(s[mt][0][r]);
          pB[r] = __builtin_amdgcn_exp2f(s[mt][1][r]);
          lsum[mt] += pA[r] + pB[r];
        }
        unsigned A0 = cvt_pk_bf16(pA[0], pA[1]);
        unsigned A1 = cvt_pk_bf16(pA[2], pA[3]);
        unsigned B0 = cvt_pk_bf16(pB[0], pB[1]);
        unsigned B1 = cvt_pk_bf16(pB[2], pB[3]);
        pl32_swap(A0, B0); pl16_swap(A0, B0);
        pl32_swap(A1, B1); pl16_swap(A1, B1);
        uint4v w; w[0] = A0; w[1] = A1; w[2] = B0; w[3] = B1;
        pfrag[mt] = __builtin_bit_cast(short8, w);
      }
#pragma unroll
      for (int dt = 0; dt < 4; ++dt) {
        int row = dt * 16 + l15;
        int g = (ks4 * 4 + quad) ^ (row & 7);
        short8 vf = *(const short8*)&Vs[cur][row * 128 + g * 8];
#pragma unroll
        for (int mt = 0; mt < 2; ++mt)
          acc_ot[mt][dt] = __builtin_amdgcn_mfma_f32_16x16x32_bf16(vf, pfrag[mt], acc_ot[mt][dt], 0, 0, 0);
      }
    }
    __syncthreads();   // implicit vmcnt(0): next tile landed; all reads of cur done
  }

#pragma unroll
  for (int mt = 0; mt < 2; ++mt) {
    float l = lsum[mt];
    l += __shfl_xor(l, 16, 64);
    l += __shfl_xor(l, 32, 64);
    float invl = 1.0f / l;
#pragma unroll
    for (int dt = 0; dt < 4; ++dt) {
      ushort4v o;
#pragma unroll
      for (int r = 0; r < 4; ++r) {
        bf16 t = __float2bfloat16(acc_ot[mt][dt][r] * invl);
        unsigned short us;
        __builtin_memcpy(&us, &t, 2);
        o[r] = us;
      }
      *(ushort4v*)(attn_o + (size_t)(b * KSEL + q0 + mt * 16 + l15) * D_ + h * 64 + dt * 16 + quad * 4) = o;
    }
  }
}

// ---------------------------------------------------------------- launch
extern "C" void kernel_launch(void* const* d_in, const int* in_sizes, int n_in,
                              void* d_out, int out_size, void* d_ws, size_t ws_size,
                              hipStream_t stream)
{
  const float* x      = (const float*)d_in[0];
  const float* router = (const float*)d_in[1];
  const float* ln1g   = (const float*)d_in[2];
  const float* ln1b   = (const float*)d_in[3];
  const float* ln2g   = (const float*)d_in[4];
  const float* ln2b   = (const float*)d_in[5];
  const float* wqkv   = (const float*)d_in[6];
  const float* wo     = (const float*)d_in[7];
  const float* w1     = (const float*)d_in[8];
  const float* w2     = (const float*)d_in[9];
  float* out = (float*)d_out;
  char* ws = (char*)d_ws;

  float* logits = (float*)(ws + 0);                 // 64 KB
  int*   sel    = (int*)  (ws + 65536);             // 32 KB
  float* rw     = (float*)(ws + 98304);             // 32 KB
  bf16* wqkvT   = (bf16*) (ws + 131072);            // 6 MB   [3072][1024]
  bf16* woT     = (bf16*) (ws + 6422528);           // 2 MB   [1024][1024]
  bf16* w1T     = (bf16*) (ws + 8519680);           // 8 MB   [4096][1024]
  bf16* w2T     = (bf16*) (ws + 16908288);          // 8 MB   [1024][4096]
  bf16* regA    = (bf16*) (ws + 25296896);          // 16 MB  h1 / attn_o / h2
  bf16* regB    = (bf16*) (ws + 42074112);          // 64 MB  qkv(48)+vt(16) then ffn_h
  bf16* vtb     = (bf16*) (ws + 42074112 + 50331648);
  float* x1     = (float*)(ws + 109182976);         // 32 MB

  copy_router<<<dim3(S_, B_), 256, 0, stream>>>(x, router, out, logits);
  topk_kernel<<<B_, 1024, 0, stream>>>(logits, sel, rw);

  wtrans<<<dim3(3072 / 32, 1024 / 32), 256, 0, stream>>>(wqkv, wqkvT, 1024, 3072);
  wtrans<<<dim3(1024 / 32, 1024 / 32), 256, 0, stream>>>(wo,   woT,   1024, 1024);
  wtrans<<<dim3(4096 / 32, 1024 / 32), 256, 0, stream>>>(w1,   w1T,   1024, 4096);
  wtrans<<<dim3(1024 / 32, 4096 / 32), 256, 0, stream>>>(w2,   w2T,   4096, 1024);

  ln_kernel<<<B_ * KSEL, 256, 0, stream>>>(nullptr, x, sel, ln1g, ln1b, regA, 1);

  // QKV: [8192x1024] * [3072x1024]^T -> bf16 [8192][3072]
  gemm_bt<0, 128><<<dim3(64, 24), 256, 0, stream>>>(regA, wqkvT, nullptr, regB, 8192, 3072, 1024,
                                                    nullptr, nullptr, nullptr, nullptr, nullptr);
  vt_transpose<<<dim3(KSEL / 32, 2, B_ * NH), 256, 0, stream>>>(regB, vtb);
  flash_kernel<<<dim3(KSEL / 128, NH, B_), 256, 0, stream>>>(regB, vtb, regA);

  // o-proj + gather residual: x1 = gather(x) + attn_o * wo
  gemm_bt<1, 128><<<dim3(64, 8), 256, 0, stream>>>(regA, woT, x1, nullptr, 8192, 1024, 1024,
                                                   x, sel, nullptr, nullptr, nullptr);
  ln_kernel<<<B_ * KSEL, 256, 0, stream>>>(x1, nullptr, nullptr, ln2g, ln2b, regA, 0);
  // FFN1 + gelu -> bf16 [8192][4096]
  gemm_bt<2, 128><<<dim3(64, 32), 256, 0, stream>>>(regA, w1T, nullptr, regB, 8192, 4096, 1024,
                                                    nullptr, nullptr, nullptr, nullptr, nullptr);
  // FFN2 + scatter: out[b,sel,:] += rw * (x1 + acc)
  gemm_bt<3, 128><<<dim3(64, 8), 256, 0, stream>>>(regB, w2T, nullptr, nullptr, 8192, 1024, 4096,
                                                   nullptr, sel, rw, x1, out);
}

// Round 6
// 586.041 us; speedup vs baseline: 1.1876x; 1.0451x over previous
//
#include <hip/hip_runtime.h>
#include <hip/hip_bf16.h>
#include <stdint.h>

typedef __hip_bfloat16 bf16;
typedef __attribute__((ext_vector_type(8))) short short8;   // 8 bf16 = 4 VGPRs (MFMA A/B frag)
typedef __attribute__((ext_vector_type(4))) float f32x4;    // MFMA C/D frag
typedef __attribute__((ext_vector_type(2))) unsigned uint2v;
typedef __attribute__((ext_vector_type(4))) unsigned uint4v;
typedef __attribute__((ext_vector_type(4))) unsigned short ushort4v;

#define B_   4
#define S_   4096
#define D_   1024
#define KSEL 2048
#define DFF  4096
#define NH   16
#define DH   64

// ---------------------------------------------------------------- helpers
static __device__ __forceinline__ void load_lds16(const void* g, void* l) {
  // async global->LDS, 16B per lane, dst = wave-uniform base + lane*16
  __builtin_amdgcn_global_load_lds((const __attribute__((address_space(1))) void*)g,
                                   (__attribute__((address_space(3))) void*)l,
                                   16, 0, 0);
}

static __device__ __forceinline__ short8 scale8(short8 v, float s) {
  short8 r;
#pragma unroll
  for (int i = 0; i < 8; ++i) {
    unsigned u = ((unsigned)(unsigned short)v[i]) << 16;
    float f = __uint_as_float(u) * s;
    bf16 o = __float2bfloat16(f);
    short t;
    __builtin_memcpy(&t, &o, 2);
    r[i] = t;
  }
  return r;
}

static __device__ __forceinline__ unsigned cvt_pk_bf16(float lo, float hi) {
  unsigned r;
  asm("v_cvt_pk_bf16_f32 %0, %1, %2" : "=v"(r) : "v"(lo), "v"(hi));
  return r;
}

static __device__ __forceinline__ void pl32_swap(unsigned &a, unsigned &b) {
#if __has_builtin(__builtin_amdgcn_permlane32_swap)
  uint2v r = __builtin_amdgcn_permlane32_swap(a, b, false, false);
  a = r[0]; b = r[1];
#else
  asm("v_permlane32_swap_b32 %0, %1" : "+v"(a), "+v"(b));
#endif
}

static __device__ __forceinline__ void pl16_swap(unsigned &a, unsigned &b) {
#if __has_builtin(__builtin_amdgcn_permlane16_swap)
  uint2v r = __builtin_amdgcn_permlane16_swap(a, b, false, false);
  a = r[0]; b = r[1];
#else
  asm("v_permlane16_swap_b32 %0, %1" : "+v"(a), "+v"(b));
#endif
}

// ---------------------------------------------------------------- 1) copy x -> out, logits = x @ router_w
__global__ __launch_bounds__(256)
void copy_router(const float* __restrict__ x, const float* __restrict__ rwts,
                 float* __restrict__ out, float* __restrict__ logits)
{
  int s = blockIdx.x, b = blockIdx.y;
  int tid = threadIdx.x;
  const float4* row = (const float4*)(x + ((size_t)b * S_ + s) * D_);
  float4 v = row[tid];
  ((float4*)(out + ((size_t)b * S_ + s) * D_))[tid] = v;
  float4 rv = ((const float4*)rwts)[tid];
  float p = v.x * rv.x + v.y * rv.y + v.z * rv.z + v.w * rv.w;
  for (int off = 32; off; off >>= 1) p += __shfl_down(p, off, 64);
  __shared__ float wsum[4];
  if ((tid & 63) == 0) wsum[tid >> 6] = p;
  __syncthreads();
  if (tid == 0) logits[(size_t)b * S_ + s] = wsum[0] + wsum[1] + wsum[2] + wsum[3];
}

// ---------------------------------------------------------------- 2) per-batch top-K: binary-search threshold select
// T = max u32 key t with count(key >= t) >= KSEL (keys monotone-encoded floats,
// held in registers). Selected set = {key > T} + first (KSEL - n_gt) elements
// with key == T in index order -- identical to stable top_k semantics.
__global__ __launch_bounds__(1024)
void topk_kernel(const float* __restrict__ logits,
                 int* __restrict__ sel, float* __restrict__ rw)
{
  __shared__ int   wredi[16];
  __shared__ float wredf[16];
  __shared__ int   woff[17];

  int b = blockIdx.x, tid = threadIdx.x;
  int lane = tid & 63, wv = tid >> 6;
  const float* L = logits + (size_t)b * S_;
  int base = tid * 4;
  float4 v = ((const float4*)L)[tid];
  // monotone key: ascending key order == ascending float order
  unsigned k0, k1, k2, k3;
  {
    unsigned u;
    u = __float_as_uint(v.x); k0 = (u & 0x80000000u) ? ~u : (u | 0x80000000u);
    u = __float_as_uint(v.y); k1 = (u & 0x80000000u) ? ~u : (u | 0x80000000u);
    u = __float_as_uint(v.z); k2 = (u & 0x80000000u) ? ~u : (u | 0x80000000u);
    u = __float_as_uint(v.w); k3 = (u & 0x80000000u) ? ~u : (u | 0x80000000u);
  }
  // block max (softmax shift; max logit value == max selected value)
  float mx = fmaxf(fmaxf(v.x, v.y), fmaxf(v.z, v.w));
  for (int off = 32; off; off >>= 1) mx = fmaxf(mx, __shfl_xor(mx, off, 64));
  if (lane == 0) wredf[wv] = mx;
  __syncthreads();
  float m = wredf[0];
  for (int w = 1; w < 16; ++w) m = fmaxf(m, wredf[w]);

  // greedy bit-by-bit threshold search (count_ge monotone non-increasing)
  unsigned T = 0;
  for (int bit = 31; bit >= 0; --bit) {
    unsigned cand = T | (1u << bit);
    int c = (int)(k0 >= cand) + (int)(k1 >= cand) + (int)(k2 >= cand) + (int)(k3 >= cand);
    for (int off = 32; off; off >>= 1) c += __shfl_xor(c, off, 64);
    __syncthreads();
    if (lane == 0) wredi[wv] = c;
    __syncthreads();
    int tot = 0;
    for (int w = 0; w < 16; ++w) tot += wredi[w];
    if (tot >= KSEL) T = cand;
  }
  // strictly-greater count
  int cg = (int)(k0 > T) + (int)(k1 > T) + (int)(k2 > T) + (int)(k3 > T);
  for (int off = 32; off; off >>= 1) cg += __shfl_xor(cg, off, 64);
  __syncthreads();
  if (lane == 0) wredi[wv] = cg;
  __syncthreads();
  int n_gt = 0;
  for (int w = 0; w < 16; ++w) n_gt += wredi[w];
  int need = KSEL - n_gt;
  // exclusive prefix of eq-flags (index order) to rank tie elements
  int e0 = (k0 == T), e1 = (k1 == T), e2 = (k2 == T), e3 = (k3 == T);
  int esum = e0 + e1 + e2 + e3;
  int eincl = esum;
  for (int off = 1; off < 64; off <<= 1) { int t = __shfl_up(eincl, off, 64); if (lane >= off) eincl += t; }
  __syncthreads();
  if (lane == 63) wredi[wv] = eincl;
  __syncthreads();
  int ebase = 0;
  for (int w = 0; w < wv; ++w) ebase += wredi[w];
  int ep = ebase + eincl - esum;
  int f0 = (k0 > T) || (e0 && ep < need); ep += e0;
  int f1 = (k1 > T) || (e1 && ep < need); ep += e1;
  int f2 = (k2 > T) || (e2 && ep < need); ep += e2;
  int f3 = (k3 > T) || (e3 && ep < need); ep += e3;
  // softmax denominator over selected
  float part = 0.f;
  if (f0) part += __expf(v.x - m);
  if (f1) part += __expf(v.y - m);
  if (f2) part += __expf(v.z - m);
  if (f3) part += __expf(v.w - m);
  for (int off = 32; off; off >>= 1) part += __shfl_xor(part, off, 64);
  __syncthreads();
  if (lane == 0) wredf[wv] = part;
  __syncthreads();
  float tot = 0.f;
  for (int w = 0; w < 16; ++w) tot += wredf[w];
  float inv = 1.0f / tot;
  // compaction: ascending-index positions via prefix scan
  int mysum = f0 + f1 + f2 + f3;
  int incl = mysum;
  for (int off = 1; off < 64; off <<= 1) { int t = __shfl_up(incl, off, 64); if (lane >= off) incl += t; }
  __syncthreads();
  if (lane == 63) wredi[wv] = incl;
  __syncthreads();
  if (tid == 0) { int s = 0; for (int w = 0; w < 16; ++w) { woff[w] = s; s += wredi[w]; } woff[16] = s; }
  __syncthreads();
  int p = woff[wv] + incl - mysum;
  float vv[4] = { v.x, v.y, v.z, v.w };
  int ff[4] = { f0, f1, f2, f3 };
  for (int q = 0; q < 4; ++q) {
    if (ff[q]) {
      sel[b * KSEL + p] = base + q;
      rw[b * KSEL + p] = __expf(vv[q] - m) * inv;
      p++;
    }
  }
}

// ---------------------------------------------------------------- 3) LayerNorm (optional gather) -> bf16
__global__ __launch_bounds__(256)
void ln_kernel(const float* __restrict__ in, const float* __restrict__ x,
               const int* __restrict__ sel,
               const float* __restrict__ g, const float* __restrict__ beta,
               bf16* __restrict__ out, int gather)
{
  int r = blockIdx.x;
  int tid = threadIdx.x;
  const float* src;
  if (gather) {
    int b = r >> 11, t = r & 2047;
    src = x + ((size_t)b * S_ + sel[b * KSEL + t]) * D_;
  } else {
    src = in + (size_t)r * D_;
  }
  float4 v = ((const float4*)src)[tid];
  float s = v.x + v.y + v.z + v.w;
  float sq = v.x * v.x + v.y * v.y + v.z * v.z + v.w * v.w;
  for (int off = 32; off; off >>= 1) { s += __shfl_down(s, off, 64); sq += __shfl_down(sq, off, 64); }
  __shared__ float wsA[4], wsB[4];
  if ((tid & 63) == 0) { wsA[tid >> 6] = s; wsB[tid >> 6] = sq; }
  __syncthreads();
  float stot = wsA[0] + wsA[1] + wsA[2] + wsA[3];
  float sqt  = wsB[0] + wsB[1] + wsB[2] + wsB[3];
  float mean = stot * (1.f / 1024.f);
  float var  = sqt * (1.f / 1024.f) - mean * mean;
  float rs = rsqrtf(var + 1e-5f);
  float4 gv = ((const float4*)g)[tid];
  float4 bv = ((const float4*)beta)[tid];
  bf16* o = out + (size_t)r * D_ + tid * 4;
  o[0] = __float2bfloat16((v.x - mean) * rs * gv.x + bv.x);
  o[1] = __float2bfloat16((v.y - mean) * rs * gv.y + bv.y);
  o[2] = __float2bfloat16((v.z - mean) * rs * gv.z + bv.z);
  o[3] = __float2bfloat16((v.w - mean) * rs * gv.w + bv.w);
}

// ---------------------------------------------------------------- 4) weight cast+transpose fp32[K][N] -> bf16[N][K]
__global__ __launch_bounds__(256)
void wtrans(const float* __restrict__ in, bf16* __restrict__ out, int K, int N)
{
  __shared__ float tile[32][33];
  int n0 = blockIdx.x * 32, k0 = blockIdx.y * 32;
  int r = threadIdx.x >> 5, c = threadIdx.x & 31;
#pragma unroll
  for (int i = 0; i < 4; ++i)
    tile[r + 8 * i][c] = in[(size_t)(k0 + r + 8 * i) * N + n0 + c];
  __syncthreads();
#pragma unroll
  for (int i = 0; i < 4; ++i)
    out[(size_t)(n0 + r + 8 * i) * K + k0 + c] = __float2bfloat16(tile[c][r + 8 * i]);
}

// ---------------------------------------------------------------- 5) V transpose: qkv[t][2048+h*64+d] -> vt[bh][d][t]
__global__ __launch_bounds__(256)
void vt_transpose(const bf16* __restrict__ qkv, bf16* __restrict__ vt)
{
  __shared__ bf16 tile[32][33];
  int bh = blockIdx.z;
  int d0 = blockIdx.y * 32;
  int t0 = blockIdx.x * 32;
  int b = bh >> 4, h = bh & 15;
  int r = threadIdx.x >> 5, c = threadIdx.x & 31;
#pragma unroll
  for (int i = 0; i < 4; ++i) {
    int t = t0 + r + 8 * i;
    tile[r + 8 * i][c] = qkv[(size_t)(b * KSEL + t) * 3072 + 2048 + h * 64 + d0 + c];
  }
  __syncthreads();
#pragma unroll
  for (int i = 0; i < 4; ++i) {
    int d = d0 + r + 8 * i;
    vt[((size_t)bh * 64 + d) * KSEL + t0 + c] = tile[c][r + 8 * i];
  }
}

// ---------------------------------------------------------------- 6) GEMM C = A(bf16 MxK) * Bt(bf16 NxK)^T  + fused epilogues
// EPI 0: store bf16            (QKV)
// EPI 1: Cf = gather(x) + acc  (o-proj residual, fp32)
// EPI 2: store bf16 gelu(acc)  (FFN1)
// EPI 3: out[b,sel,n] += rw*(x1 + acc)  (FFN2 + final scatter; each (gm,gn)
//        owned by exactly one thread -- sel entries distinct -- plain RMW)
template<int EPI, int TN>
__global__ __launch_bounds__(256)
void gemm_bt(const bf16* __restrict__ A, const bf16* __restrict__ Bt,
             float* __restrict__ Cf, bf16* __restrict__ Cb,
             int M, int N, int K,
             const float* __restrict__ xin, const int* __restrict__ sel,
             const float* __restrict__ rw, const float* __restrict__ x1,
             float* __restrict__ outp)
{
  constexpr int NT = TN / 32;
  constexpr int WN = TN / 2;
  __shared__ bf16 As[128 * 64];
  __shared__ bf16 Bs[TN * 64];
  const int tid = threadIdx.x;
  const int wid = tid >> 6;
  const int lane = tid & 63;
  const int l15 = lane & 15;
  const int quad = lane >> 4;
  const int wm = wid >> 1, wn = wid & 1;
  const int bm = blockIdx.x * 128;
  const int bn = blockIdx.y * TN;

  const int srow = lane >> 3;
  const int sgrp = (lane & 7) ^ srow;

  f32x4 acc[4][NT] = {};

  for (int k0 = 0; k0 < K; k0 += 64) {
#pragma unroll
    for (int c2 = 0; c2 < 4; ++c2) {
      int c = wid * 4 + c2;
      const bf16* ga = A + (size_t)(bm + c * 8 + srow) * K + (k0 + sgrp * 8);
      load_lds16(ga, &As[c * 512]);
    }
#pragma unroll
    for (int c2 = 0; c2 < TN / 32; ++c2) {
      int c = wid * (TN / 32) + c2;
      const bf16* gb = Bt + (size_t)(bn + c * 8 + srow) * K + (k0 + sgrp * 8);
      load_lds16(gb, &Bs[c * 512]);
    }
    __syncthreads();
#pragma unroll
    for (int ks = 0; ks < 2; ++ks) {
      short8 af[4], bfv[NT];
#pragma unroll
      for (int mt = 0; mt < 4; ++mt) {
        int row = wm * 64 + mt * 16 + l15;
        int cg = (ks * 4 + quad) ^ (row & 7);
        af[mt] = *(const short8*)&As[row * 64 + cg * 8];
      }
#pragma unroll
      for (int nt = 0; nt < NT; ++nt) {
        int row = wn * WN + nt * 16 + l15;
        int cg = (ks * 4 + quad) ^ (row & 7);
        bfv[nt] = *(const short8*)&Bs[row * 64 + cg * 8];
      }
#pragma unroll
      for (int mt = 0; mt < 4; ++mt)
#pragma unroll
        for (int nt = 0; nt < NT; ++nt)
          acc[mt][nt] = __builtin_amdgcn_mfma_f32_16x16x32_bf16(af[mt], bfv[nt], acc[mt][nt], 0, 0, 0);
    }
    __syncthreads();
  }

#pragma unroll
  for (int mt = 0; mt < 4; ++mt) {
#pragma unroll
    for (int r = 0; r < 4; ++r) {
      int gm = bm + wm * 64 + mt * 16 + quad * 4 + r;
      int bb = gm >> 11, tt = gm & 2047;
      int sr = 0; float rwv = 0.f;
      if (EPI == 1 || EPI == 3) sr = sel[bb * KSEL + tt];
      if (EPI == 3) rwv = rw[bb * KSEL + tt];
#pragma unroll
      for (int nt = 0; nt < NT; ++nt) {
        int gn = bn + wn * WN + nt * 16 + l15;
        float v = acc[mt][nt][r];
        if (EPI == 0) {
          Cb[(size_t)gm * N + gn] = __float2bfloat16(v);
        } else if (EPI == 1) {
          float xv = xin[((size_t)bb * S_ + sr) * D_ + gn];
          Cf[(size_t)gm * N + gn] = xv + v;
        } else if (EPI == 2) {
          float u = v;
          float cc = 0.7978845608028654f * (u + 0.044715f * u * u * u);
          float e = __expf(2.f * cc);
          float th = 1.f - 2.f / (e + 1.f);
          Cb[(size_t)gm * N + gn] = __float2bfloat16(0.5f * u * (1.f + th));
        } else {
          float v2 = rwv * (x1[(size_t)gm * D_ + gn] + v);
          outp[((size_t)bb * S_ + sr) * D_ + gn] += v2;
        }
      }
    }
  }
}

// ---------------------------------------------------------------- 7) flash attention, swapped-operand + in-register P
// Single-buffer staging (two barriers per tile; cross-block TLP hides the
// staging drain -- measured better than explicit dbuf, R4 post-mortem).
// l-via-MFMA: one mfma(ones_A, pfrag, acc_l) per (mt,ks4). A=ones makes every
// C row = sum_k P^T[k][q]; the B-frag spans all 32 k across quads, so the MFMA
// also does the cross-quad reduction. acc_l accumulates over ks4 and tiles;
// epilogue reads acc_l[mt][0] directly -- no lsum VALU adds, no shuffles.
__global__ __launch_bounds__(256)
void flash_kernel(const bf16* __restrict__ qkv, const bf16* __restrict__ vt,
                  bf16* __restrict__ attn_o)
{
  __shared__ bf16 Ks[128 * 64];        // [token][dh]   16 KB
  __shared__ bf16 Vs[64 * 128];        // [dh][token]   16 KB
  int qt = blockIdx.x, h = blockIdx.y, b = blockIdx.z;
  int tid = threadIdx.x, wid = tid >> 6, lane = tid & 63;
  int l15 = lane & 15, quad = lane >> 4;
  int q0 = qt * 128 + wid * 32;

  const int srowK = lane >> 3, sgK = lane & 7;
  const int srowV = lane >> 4, sgV = lane & 15;

  short8 qf[2][2];
#pragma unroll
  for (int mt = 0; mt < 2; ++mt)
#pragma unroll
    for (int ks = 0; ks < 2; ++ks) {
      const bf16* p = qkv + (size_t)(b * KSEL + q0 + mt * 16 + l15) * 3072 + h * 64 + ks * 32 + quad * 8;
      qf[mt][ks] = scale8(*(const short8*)p, 0.125f * 1.44269504f);
    }

  short8 ones8;
  {
    short o1 = (short)0x3F80;   // bf16 1.0
#pragma unroll
    for (int i = 0; i < 8; ++i) ones8[i] = o1;
  }

  f32x4 acc_ot[2][4] = {};   // O^T: lane holds O^T[dh=dt*16+quad*4+r][q=mt*16+l15]
  f32x4 acc_l[2] = {};       // l:   every row identical; l(q=l15) = acc_l[mt][0]

  const bf16* Vg = vt + (size_t)(b * NH + h) * 64 * KSEL;

  for (int kt = 0; kt < KSEL / 128; ++kt) {
    int tok0 = b * KSEL + kt * 128;
    __syncthreads();   // previous tile's LDS reads complete
#pragma unroll
    for (int i = 0; i < 4; ++i) {
      int c = wid * 4 + i;
      const bf16* ga = qkv + (size_t)(tok0 + c * 8 + srowK) * 3072 + 1024 + h * 64 + ((sgK ^ srowK) * 8);
      load_lds16(ga, &Ks[c * 512]);
      int vr = c * 4 + srowV;
      const bf16* gv = Vg + (size_t)vr * KSEL + kt * 128 + ((sgV ^ (vr & 7)) * 8);
      load_lds16(gv, &Vs[c * 512]);
    }
    __syncthreads();   // staging drained (vmcnt(0) before s_barrier)

#pragma unroll
    for (int ks4 = 0; ks4 < 4; ++ks4) {
      // ---- QK^T (swapped): S^T tiles for the two 16-token groups of this 32-k block
      f32x4 s[2][2] = {};
#pragma unroll
      for (int u = 0; u < 2; ++u) {
        int row = (ks4 * 2 + u) * 16 + l15;
#pragma unroll
        for (int ks = 0; ks < 2; ++ks) {
          int g = (ks * 4 + quad) ^ (row & 7);
          short8 kf = *(const short8*)&Ks[row * 64 + g * 8];
#pragma unroll
          for (int mt = 0; mt < 2; ++mt)
            s[mt][u] = __builtin_amdgcn_mfma_f32_16x16x32_bf16(kf, qf[mt][ks], s[mt][u], 0, 0, 0);
        }
      }
      // ---- softmax + in-register transpose into P^T B-fragments
      short8 pfrag[2];
#pragma unroll
      for (int mt = 0; mt < 2; ++mt) {
        float pA[4], pB[4];
#pragma unroll
        for (int r = 0; r < 4; ++r) {
          pA[r] = __builtin_amdgcn_exp2f(s[mt][0][r]);
          pB[r] = __builtin_amdgcn_exp2f(s[mt][1][r]);
        }
        unsigned A0 = cvt_pk_bf16(pA[0], pA[1]);
        unsigned A1 = cvt_pk_bf16(pA[2], pA[3]);
        unsigned B0 = cvt_pk_bf16(pB[0], pB[1]);
        unsigned B1 = cvt_pk_bf16(pB[2], pB[3]);
        pl32_swap(A0, B0); pl16_swap(A0, B0);
        pl32_swap(A1, B1); pl16_swap(A1, B1);
        uint4v w; w[0] = A0; w[1] = A1; w[2] = B0; w[3] = B1;
        pfrag[mt] = __builtin_bit_cast(short8, w);
        // l partial for this 32-k block via MFMA (full cross-quad k-sum)
        acc_l[mt] = __builtin_amdgcn_mfma_f32_16x16x32_bf16(ones8, pfrag[mt], acc_l[mt], 0, 0, 0);
      }
      // ---- PV (transposed): O^T += V^T[:, k-block] * P^T[k-block, :]
#pragma unroll
      for (int dt = 0; dt < 4; ++dt) {
        int row = dt * 16 + l15;
        int g = (ks4 * 4 + quad) ^ (row & 7);
        short8 vf = *(const short8*)&Vs[row * 128 + g * 8];
#pragma unroll
        for (int mt = 0; mt < 2; ++mt)
          acc_ot[mt][dt] = __builtin_amdgcn_mfma_f32_16x16x32_bf16(vf, pfrag[mt], acc_ot[mt][dt], 0, 0, 0);
      }
    }
  }
#pragma unroll
  for (int mt = 0; mt < 2; ++mt) {
    float invl = 1.0f / acc_l[mt][0];
#pragma unroll
    for (int dt = 0; dt < 4; ++dt) {
      ushort4v o;
#pragma unroll
      for (int r = 0; r < 4; ++r) {
        bf16 t = __float2bfloat16(acc_ot[mt][dt][r] * invl);
        unsigned short us;
        __builtin_memcpy(&us, &t, 2);
        o[r] = us;
      }
      *(ushort4v*)(attn_o + (size_t)(b * KSEL + q0 + mt * 16 + l15) * D_ + h * 64 + dt * 16 + quad * 4) = o;
    }
  }
}

// ---------------------------------------------------------------- launch
extern "C" void kernel_launch(void* const* d_in, const int* in_sizes, int n_in,
                              void* d_out, int out_size, void* d_ws, size_t ws_size,
                              hipStream_t stream)
{
  const float* x      = (const float*)d_in[0];
  const float* router = (const float*)d_in[1];
  const float* ln1g   = (const float*)d_in[2];
  const float* ln1b   = (const float*)d_in[3];
  const float* ln2g   = (const float*)d_in[4];
  const float* ln2b   = (const float*)d_in[5];
  const float* wqkv   = (const float*)d_in[6];
  const float* wo     = (const float*)d_in[7];
  const float* w1     = (const float*)d_in[8];
  const float* w2     = (const float*)d_in[9];
  float* out = (float*)d_out;
  char* ws = (char*)d_ws;

  float* logits = (float*)(ws + 0);                 // 64 KB
  int*   sel    = (int*)  (ws + 65536);             // 32 KB
  float* rw     = (float*)(ws + 98304);             // 32 KB
  bf16* wqkvT   = (bf16*) (ws + 131072);            // 6 MB   [3072][1024]
  bf16* woT     = (bf16*) (ws + 6422528);           // 2 MB   [1024][1024]
  bf16* w1T     = (bf16*) (ws + 8519680);            // 8 MB   [4096][1024]
  bf16* w2T     = (bf16*) (ws + 16908288);          // 8 MB   [1024][4096]
  bf16* regA    = (bf16*) (ws + 25296896);          // 16 MB  h1 / attn_o / h2
  bf16* regB    = (bf16*) (ws + 42074112);          // 64 MB  qkv(48)+vt(16) then ffn_h
  bf16* vtb     = (bf16*) (ws + 42074112 + 50331648);
  float* x1     = (float*)(ws + 109182976);         // 32 MB

  copy_router<<<dim3(S_, B_), 256, 0, stream>>>(x, router, out, logits);
  topk_kernel<<<B_, 1024, 0, stream>>>(logits, sel, rw);

  wtrans<<<dim3(3072 / 32, 1024 / 32), 256, 0, stream>>>(wqkv, wqkvT, 1024, 3072);
  wtrans<<<dim3(1024 / 32, 1024 / 32), 256, 0, stream>>>(wo,   woT,   1024, 1024);
  wtrans<<<dim3(4096 / 32, 1024 / 32), 256, 0, stream>>>(w1,   w1T,   1024, 4096);
  wtrans<<<dim3(1024 / 32, 4096 / 32), 256, 0, stream>>>(w2,   w2T,   4096, 1024);

  ln_kernel<<<B_ * KSEL, 256, 0, stream>>>(nullptr, x, sel, ln1g, ln1b, regA, 1);

  // QKV: [8192x1024] * [3072x1024]^T -> bf16 [8192][3072]
  gemm_bt<0, 128><<<dim3(64, 24), 256, 0, stream>>>(regA, wqkvT, nullptr, regB, 8192, 3072, 1024,
                                                    nullptr, nullptr, nullptr, nullptr, nullptr);
  vt_transpose<<<dim3(KSEL / 32, 2, B_ * NH), 256, 0, stream>>>(regB, vtb);
  flash_kernel<<<dim3(KSEL / 128, NH, B_), 256, 0, stream>>>(regB, vtb, regA);

  // o-proj + gather residual: x1 = gather(x) + attn_o * wo
  gemm_bt<1, 128><<<dim3(64, 8), 256, 0, stream>>>(regA, woT, x1, nullptr, 8192, 1024, 1024,
                                                   x, sel, nullptr, nullptr, nullptr);
  ln_kernel<<<B_ * KSEL, 256, 0, stream>>>(x1, nullptr, nullptr, ln2g, ln2b, regA, 0);
  // FFN1 + gelu -> bf16 [8192][4096]
  gemm_bt<2, 128><<<dim3(64, 32), 256, 0, stream>>>(regA, w1T, nullptr, regB, 8192, 4096, 1024,
                                                    nullptr, nullptr, nullptr, nullptr, nullptr);
  // FFN2 + scatter: out[b,sel,:] += rw * (x1 + acc)
  gemm_bt<3, 128><<<dim3(64, 8), 256, 0, stream>>>(regB, w2T, nullptr, nullptr, 8192, 1024, 4096,
                                                   nullptr, sel, rw, x1, out);
}